// Round 8
// baseline (3986.172 us; speedup 1.0000x reference)
//
#include <hip/hip_runtime.h>

typedef unsigned short u16;
typedef unsigned int   u32;
typedef __attribute__((ext_vector_type(8))) short s8v;   // 8 x bf16 bits (4 VGPRs)
typedef __attribute__((ext_vector_type(4))) float f4v;   // MFMA accumulator

#define B_SZ  64
#define T_LEN 512
#define U_DIM 256
#define E_DIM 300
#define EP    320          // E padded to multiple of 32
#define G3    768          // 3*U
#define NTOT  1536         // both directions concatenated
#define C_DIM 20
#define BT    (B_SZ*T_LEN)

__device__ __forceinline__ float bf2f(u16 h){ return __uint_as_float(((u32)h)<<16); }
__device__ __forceinline__ u16 f2bf(float f){
  u32 u = __float_as_uint(f);
  u32 r = (u + 0x7FFFu + ((u>>16)&1u)) >> 16;   // RNE
  return (u16)r;
}

// ------------- embedding gather f32 -> bf16, K-pad (300 -> 320, zeros) --------
__global__ void embed_pad(const int* __restrict__ x, const float* __restrict__ emb,
                          u16* __restrict__ e){
  int idx = blockIdx.x*256 + threadIdx.x;
  if(idx >= BT*EP) return;
  int row = idx / EP, col = idx - row*EP;
  u16 v = 0;
  if(col < E_DIM) v = f2bf(emb[(size_t)x[row]*E_DIM + col]);
  e[idx] = v;
}

// ------ transpose + concat two f32 [K,768] sources -> bf16 dst[N][Kp] ---------
__global__ void transpose_cc(const float* __restrict__ A, const float* __restrict__ Bm,
                             u16* __restrict__ dst, int K, int Kp, int N){
  int idx = blockIdx.x*256 + threadIdx.x;
  if(idx >= N*Kp) return;
  int n = idx / Kp, k = idx - n*Kp;
  u16 v = 0;
  if(k < K){
    const float* s = (n < G3) ? A : Bm;
    int nn = (n < G3) ? n : n - G3;
    v = f2bf(s[(size_t)k*G3 + nn]);
  }
  dst[idx] = v;
}

// ---------------- GEMM: C[M,1536] = A[M,Kp] @ BT^T + bias (bf16 out) ----------
__global__ __launch_bounds__(256) void gemm_bt(
    const u16* __restrict__ A, const u16* __restrict__ BT_, u16* __restrict__ C,
    int Kp, const float* __restrict__ biasA, const float* __restrict__ biasB)
{
  __shared__ u16 Al[128][40];   // +8 pad breaks bank collisions
  __shared__ u16 Bl[128][40];
  int tid = threadIdx.x;
  int w = tid>>6, l = tid&63, lc = l&15, quad = l>>4;
  int wm = w>>1, wn = w&1;
  int mb = blockIdx.y*128, nb = blockIdx.x*128;

  f4v acc[4][4];
  #pragma unroll
  for(int i=0;i<4;i++)
    #pragma unroll
    for(int j=0;j<4;j++) acc[i][j] = (f4v){0.f,0.f,0.f,0.f};

  int nk = Kp >> 5;
  for(int kt=0; kt<nk; kt++){
    __syncthreads();
    {
      int c0 = tid, c1 = tid + 256;
      int r0 = c0>>2, k80 = c0&3;
      int r1 = c1>>2, k81 = c1&3;
      *(s8v*)&Al[r0][k80*8] = *(const s8v*)(A   + (size_t)(mb+r0)*Kp + kt*32 + k80*8);
      *(s8v*)&Al[r1][k81*8] = *(const s8v*)(A   + (size_t)(mb+r1)*Kp + kt*32 + k81*8);
      *(s8v*)&Bl[r0][k80*8] = *(const s8v*)(BT_ + (size_t)(nb+r0)*Kp + kt*32 + k80*8);
      *(s8v*)&Bl[r1][k81*8] = *(const s8v*)(BT_ + (size_t)(nb+r1)*Kp + kt*32 + k81*8);
    }
    __syncthreads();
    s8v af[4], bf[4];
    #pragma unroll
    for(int i=0;i<4;i++) af[i] = *(const s8v*)&Al[wm*64 + i*16 + lc][quad*8];
    #pragma unroll
    for(int j=0;j<4;j++) bf[j] = *(const s8v*)&Bl[wn*64 + j*16 + lc][quad*8];
    #pragma unroll
    for(int i=0;i<4;i++)
      #pragma unroll
      for(int j=0;j<4;j++)
        acc[i][j] = __builtin_amdgcn_mfma_f32_16x16x32_bf16(af[i], bf[j], acc[i][j],0,0,0);
  }
  #pragma unroll
  for(int j=0;j<4;j++){
    int col = nb + wn*64 + j*16 + lc;
    float bias = (col < G3) ? biasA[col] : biasB[col - G3];
    #pragma unroll
    for(int i=0;i<4;i++){
      int row0 = mb + wm*64 + i*16 + quad*4;
      #pragma unroll
      for(int r=0;r<4;r++)
        C[(size_t)(row0+r)*NTOT + col] = f2bf(acc[i][j][r] + bias);
    }
  }
}

// ---------------- GRU scan, one layer both directions -------------------------
// grid = 8 blocks: dir = blockIdx&1, batch-group = blockIdx>>1 (16 batches each).
// 512 threads = 8 waves; wave w owns u in [32w,32w+32): gate cols {g*256+32w..+32}.
// rk residency (R7 post-mortem: arch-VGPR class caps at 128 due to accum_offset
// split of the unified file; AGPRs sit idle):
//   ktiles 0-5 (36 frags, 144 regs): 28 frags pinned in AGPRs ("a"), 8 in VGPRs.
//   ktiles 6-7 in LDS (98 KB), emitted as intrinsics BEFORE and AFTER the asm
//   chain so the compiler's hazard recognizer covers VALU<->MFMA transitions.
// Asm-internal deps are same-D MFMA accumulate chains: 0 wait states per ISA.
template<int MODE>
__global__ __attribute__((amdgpu_flat_work_group_size(512,512), amdgpu_waves_per_eu(2,2)))
void gru_scan(
    const u16* __restrict__ xw,    // [BT,1536] bf16 (= X@K + b0, both dirs)
    const u16* __restrict__ rkT,   // [2][768][256] bf16 transposed recurrent kernels
    const float* __restrict__ bF, const float* __restrict__ bB,  // b[2][768] f32
    u16* __restrict__ h1out,       // MODE 0: [BT,512]
    float* __restrict__ h2out)     // MODE 1: [64,512] final states
{
  int dir = blockIdx.x & 1, grp = blockIdx.x >> 1;
  int b0 = grp*16;
  int tid = threadIdx.x;
  int w = tid>>6, l = tid&63, lc = l&15, quad = l>>4;

  __shared__ u16 hb[2][16][264];   // double-buffered h (bf16), +8 pad (2-way banks: free)
  __shared__ u16 rkl[G3][72];      // rk k=[192,256) per col; 64 elems + 8 pad
  for(int i=tid; i<2*16*264; i+=512) ((u16*)hb)[i] = 0;

  const u16*   rkd  = rkT + (size_t)dir*G3*U_DIM;
  const float* bias = (dir ? bB : bF) + G3;   // row 1 = recurrent bias

  // stage rkl: 768 rows x 64 elems as s8v chunks
  for(int idx=tid; idx<G3*8; idx+=512){
    int row = idx>>3, c8 = idx&7;
    *(s8v*)&rkl[row][c8*8] = *(const s8v*)(rkd + (size_t)row*U_DIM + 192 + c8*8);
  }

  // register-resident B-fragments for ktiles 0..5: f=(g*2+s)*6+kt, 36 frags.
  // f<28 -> AGPR class; else -> arch-VGPR class.
  s8v brkA[28], brkV[8];
  #pragma unroll
  for(int f=0; f<36; f++){
    int g = f/12, s = (f/6)&1, kt = f%6;
    int n = g*256 + w*32 + s*16 + lc;
    s8v v = *(const s8v*)(rkd + (size_t)n*U_DIM + kt*32 + quad*8);
    if(f < 28) brkA[f] = v; else brkV[f-28] = v;
  }
  #pragma unroll
  for(int i=0;i<28;i++) asm volatile("" : "+a"(brkA[i]));
  #pragma unroll
  for(int i=0;i<8;i++)  asm volatile("" : "+v"(brkV[i]));

  float bg[3][2];
  #pragma unroll
  for(int g=0;g<3;g++)
    #pragma unroll
    for(int s=0;s<2;s++)
      bg[g][s] = bias[g*256 + w*32 + s*16 + lc];

  int t0 = dir ? (T_LEN-1) : 0;
  long tstride  = dir ? -(long)NTOT      : (long)NTOT;       // xw elems/step
  long hstride  = dir ? -(long)(2*U_DIM) : (long)(2*U_DIM);  // h1out elems/step

  const u16* xwp[4];
  u16* hop[4];
  #pragma unroll
  for(int r=0;r<4;r++){
    int m = quad*4 + r;
    xwp[r] = xw + ((size_t)(b0+m)*T_LEN + t0)*NTOT + dir*G3 + w*32 + lc;
    hop[r] = (MODE==0) ? (h1out + ((size_t)(b0+m)*T_LEN + t0)*(2*U_DIM) + dir*U_DIM + w*32 + lc)
                       : nullptr;
  }

  __syncthreads();

  int cur = 0;
  for(int step=0; step<T_LEN; step++){
    // xw loads for this step (independent of h -> issue before MFMA)
    u16 xu[3][2][4];
    #pragma unroll
    for(int r=0;r<4;r++)
      #pragma unroll
      for(int g=0;g<3;g++)
        #pragma unroll
        for(int s=0;s<2;s++)
          xu[g][s][r] = xwp[r][g*256 + s*16];

    f4v acc[3][2];
    #pragma unroll
    for(int g=0;g<3;g++)
      #pragma unroll
      for(int s=0;s<2;s++) acc[g][s] = (f4v){0.f,0.f,0.f,0.f};

    // ktile 6 from LDS (intrinsic: visible def covers VALU-init -> MFMA hazard)
    {
      s8v a = *(const s8v*)&hb[cur][lc][6*32 + quad*8];
      #pragma unroll
      for(int g=0;g<3;g++)
        #pragma unroll
        for(int s=0;s<2;s++){
          int n = g*256 + w*32 + s*16 + lc;
          s8v b = *(const s8v*)&rkl[n][quad*8];
          acc[g][s] = __builtin_amdgcn_mfma_f32_16x16x32_bf16(a, b, acc[g][s],0,0,0);
        }
    }
    // ktiles 0..5 from registers (inline asm; B in AGPR or VGPR class)
    #pragma unroll
    for(int kt=0; kt<6; kt++){
      s8v a = *(const s8v*)&hb[cur][lc][kt*32 + quad*8];
      #pragma unroll
      for(int g=0;g<3;g++)
        #pragma unroll
        for(int s=0;s<2;s++){
          int f = (g*2+s)*6 + kt;
          if(f < 28)
            asm("v_mfma_f32_16x16x32_bf16 %0, %1, %2, %0"
                : "+v"(acc[g][s]) : "v"(a), "a"(brkA[f]));
          else
            asm("v_mfma_f32_16x16x32_bf16 %0, %1, %2, %0"
                : "+v"(acc[g][s]) : "v"(a), "v"(brkV[f-28]));
        }
    }
    // ktile 7 from LDS (intrinsic: visible def covers MFMA -> VALU-read hazard)
    {
      s8v a = *(const s8v*)&hb[cur][lc][7*32 + quad*8];
      #pragma unroll
      for(int g=0;g<3;g++)
        #pragma unroll
        for(int s=0;s<2;s++){
          int n = g*256 + w*32 + s*16 + lc;
          s8v b = *(const s8v*)&rkl[n][32 + quad*8];
          acc[g][s] = __builtin_amdgcn_mfma_f32_16x16x32_bf16(a, b, acc[g][s],0,0,0);
        }
    }

    #pragma unroll
    for(int s=0;s<2;s++){
      int u = w*32 + s*16 + lc;
      #pragma unroll
      for(int r=0;r<4;r++){
        int m = quad*4 + r;
        float zf = acc[0][s][r] + bg[0][s] + bf2f(xu[0][s][r]);
        float rf = acc[1][s][r] + bg[1][s] + bf2f(xu[1][s][r]);
        float rh = acc[2][s][r] + bg[2][s];
        float xh = bf2f(xu[2][s][r]);
        zf = 1.f / (1.f + __expf(-zf));
        rf = 1.f / (1.f + __expf(-rf));
        float hc = xh + rf*rh;
        hc = fminf(fmaxf(hc, -15.f), 15.f);
        float e2 = __expf(2.f*hc);
        float th = (e2 - 1.f) / (e2 + 1.f);
        float hp = bf2f(hb[cur][m][u]);
        float hn = zf*hp + (1.f - zf)*th;
        u16 hbf = f2bf(hn);
        hb[cur^1][m][u] = hbf;
        if(MODE == 0)
          hop[r][s*16] = hbf;
        else if(step == T_LEN-1)
          h2out[(size_t)(b0+m)*(2*U_DIM) + dir*U_DIM + u] = hn;
      }
    }

    #pragma unroll
    for(int r=0;r<4;r++){
      xwp[r] += tstride;
      if(MODE==0) hop[r] += hstride;
    }
    __syncthreads();
    cur ^= 1;
  }
}

// ---------------- final projection + softmax (f32 output) ---------------------
__global__ void out_softmax(const float* __restrict__ h2, const float* __restrict__ wout,
                            const float* __restrict__ bout, float* __restrict__ out)
{
  __shared__ float lg[C_DIM];
  int b = blockIdx.x, l = threadIdx.x;   // 64 threads = 1 wave
  float acc[C_DIM];
  #pragma unroll
  for(int c=0;c<C_DIM;c++) acc[c] = 0.f;
  for(int k=l; k<2*U_DIM; k+=64){
    float hv = h2[b*2*U_DIM + k];
    #pragma unroll
    for(int c=0;c<C_DIM;c++) acc[c] += hv * wout[k*C_DIM + c];
  }
  #pragma unroll
  for(int c=0;c<C_DIM;c++){
    float v = acc[c];
    for(int off=32; off; off>>=1) v += __shfl_down(v, off);
    if(l==0) lg[c] = v + bout[c];
  }
  __syncthreads();
  if(l==0){
    float mx = lg[0];
    for(int c=1;c<C_DIM;c++) mx = fmaxf(mx, lg[c]);
    float sum = 0.f, ex[C_DIM];
    for(int c=0;c<C_DIM;c++){ ex[c] = __expf(lg[c]-mx); sum += ex[c]; }
    for(int c=0;c<C_DIM;c++) out[b*C_DIM + c] = ex[c]/sum;
  }
}

extern "C" void kernel_launch(void* const* d_in, const int* in_sizes, int n_in,
                              void* d_out, int out_size, void* d_ws, size_t ws_size,
                              hipStream_t stream)
{
  const int*   x    = (const int*)d_in[0];
  const float* emb  = (const float*)d_in[1];
  const float* k1f  = (const float*)d_in[2];
  const float* rk1f = (const float*)d_in[3];
  const float* b1f  = (const float*)d_in[4];
  const float* k1b  = (const float*)d_in[5];
  const float* rk1b = (const float*)d_in[6];
  const float* b1b  = (const float*)d_in[7];
  const float* k2f  = (const float*)d_in[8];
  const float* rk2f = (const float*)d_in[9];
  const float* b2f  = (const float*)d_in[10];
  const float* k2b  = (const float*)d_in[11];
  const float* rk2b = (const float*)d_in[12];
  const float* b2b  = (const float*)d_in[13];
  const float* wout = (const float*)d_in[14];
  const float* bout = (const float*)d_in[15];

  // workspace layout: small buffers first, then h1/e_pad (aliased), then xwb
  char* ws = (char*)d_ws;
  u16*  k1t   = (u16*)(ws);                       // 983,040 B     [1536,320]
  u16*  k2t   = (u16*)(ws + 983040);              // 1,572,864 B   [1536,512]
  u16*  rkt   = (u16*)(ws + 2555904);             // 1,572,864 B   4x[768,256]
  float* h2   = (float*)(ws + 4128768);           // 131,072 B     [64,512]
  u16*  h1    = (u16*)(ws + 4259840);             // 33,554,432 B  [BT,512]
  u16*  e_pad = (u16*)(ws + 4259840);             // 20,971,520 B  [BT,320] (alias h1)
  u16*  xwb   = (u16*)(ws + 37814272);            // 100,663,296 B [BT,1536]

  transpose_cc<<<(NTOT*EP +255)/256,256,0,stream>>>(k1f, k1b, k1t, E_DIM, EP, NTOT);
  transpose_cc<<<(NTOT*512+255)/256,256,0,stream>>>(k2f, k2b, k2t, 512, 512, NTOT);
  transpose_cc<<<(G3*U_DIM+255)/256,256,0,stream>>>(rk1f, rk1f, rkt,                U_DIM, U_DIM, G3);
  transpose_cc<<<(G3*U_DIM+255)/256,256,0,stream>>>(rk1b, rk1b, rkt + 1*G3*U_DIM,   U_DIM, U_DIM, G3);
  transpose_cc<<<(G3*U_DIM+255)/256,256,0,stream>>>(rk2f, rk2f, rkt + 2*G3*U_DIM,   U_DIM, U_DIM, G3);
  transpose_cc<<<(G3*U_DIM+255)/256,256,0,stream>>>(rk2b, rk2b, rkt + 3*G3*U_DIM,   U_DIM, U_DIM, G3);

  embed_pad<<<(BT*EP)/256,256,0,stream>>>(x, emb, e_pad);

  // layer 1: xw = e @ K1 + b0 ; scan -> h1
  gemm_bt<<<dim3(12,256),256,0,stream>>>(e_pad, k1t, xwb, EP, b1f, b1b);
  gru_scan<0><<<8,512,0,stream>>>(xwb, rkt, b1f, b1b, h1, nullptr);

  // layer 2: xw = h1 @ K2 + b0 ; scan -> h2 (final states only)
  gemm_bt<<<dim3(12,256),256,0,stream>>>(h1, k2t, xwb, 512, b2f, b2b);
  gru_scan<1><<<8,512,0,stream>>>(xwb, rkt + 2*G3*U_DIM, b2f, b2b, nullptr, h2);

  out_softmax<<<64,64,0,stream>>>(h2, wout, bout, (float*)d_out);
}

// Round 9
// 3750.987 us; speedup vs baseline: 1.0627x; 1.0627x over previous
//
#include <hip/hip_runtime.h>

typedef unsigned short u16;
typedef unsigned int   u32;
typedef unsigned long long u64;
typedef __attribute__((ext_vector_type(8))) short s8v;   // 8 x bf16 bits (4 VGPRs)
typedef __attribute__((ext_vector_type(4))) float f4v;   // MFMA accumulator

#define B_SZ  64
#define T_LEN 512
#define U_DIM 256
#define E_DIM 300
#define EP    320          // E padded to multiple of 32
#define G3    768          // 3*U
#define NTOT  1536         // both directions concatenated
#define C_DIM 20
#define BT    (B_SZ*T_LEN)
#define NC    192          // gate-cols per scan block (3 gates x 64 u)

__device__ __forceinline__ float bf2f(u16 h){ return __uint_as_float(((u32)h)<<16); }
__device__ __forceinline__ u16 f2bf(float f){
  u32 u = __float_as_uint(f);
  u32 r = (u + 0x7FFFu + ((u>>16)&1u)) >> 16;   // RNE
  return (u16)r;
}

// ------------- embedding gather f32 -> bf16, K-pad (300 -> 320, zeros) --------
__global__ void embed_pad(const int* __restrict__ x, const float* __restrict__ emb,
                          u16* __restrict__ e){
  int idx = blockIdx.x*256 + threadIdx.x;
  if(idx >= BT*EP) return;
  int row = idx / EP, col = idx - row*EP;
  u16 v = 0;
  if(col < E_DIM) v = f2bf(emb[(size_t)x[row]*E_DIM + col]);
  e[idx] = v;
}

// ------ transpose + concat two f32 [K,768] sources -> bf16 dst[N][Kp] ---------
__global__ void transpose_cc(const float* __restrict__ A, const float* __restrict__ Bm,
                             u16* __restrict__ dst, int K, int Kp, int N){
  int idx = blockIdx.x*256 + threadIdx.x;
  if(idx >= N*Kp) return;
  int n = idx / Kp, k = idx - n*Kp;
  u16 v = 0;
  if(k < K){
    const float* s = (n < G3) ? A : Bm;
    int nn = (n < G3) ? n : n - G3;
    v = f2bf(s[(size_t)k*G3 + nn]);
  }
  dst[idx] = v;
}

// ---------------- GEMM: C[M,1536] = A[M,Kp] @ BT^T + bias (bf16 out) ----------
__global__ __launch_bounds__(256) void gemm_bt(
    const u16* __restrict__ A, const u16* __restrict__ BT_, u16* __restrict__ C,
    int Kp, const float* __restrict__ biasA, const float* __restrict__ biasB)
{
  __shared__ u16 Al[128][40];   // +8 pad breaks bank collisions
  __shared__ u16 Bl[128][40];
  int tid = threadIdx.x;
  int w = tid>>6, l = tid&63, lc = l&15, quad = l>>4;
  int wm = w>>1, wn = w&1;
  int mb = blockIdx.y*128, nb = blockIdx.x*128;

  f4v acc[4][4];
  #pragma unroll
  for(int i=0;i<4;i++)
    #pragma unroll
    for(int j=0;j<4;j++) acc[i][j] = (f4v){0.f,0.f,0.f,0.f};

  int nk = Kp >> 5;
  for(int kt=0; kt<nk; kt++){
    __syncthreads();
    {
      int c0 = tid, c1 = tid + 256;
      int r0 = c0>>2, k80 = c0&3;
      int r1 = c1>>2, k81 = c1&3;
      *(s8v*)&Al[r0][k80*8] = *(const s8v*)(A   + (size_t)(mb+r0)*Kp + kt*32 + k80*8);
      *(s8v*)&Al[r1][k81*8] = *(const s8v*)(A   + (size_t)(mb+r1)*Kp + kt*32 + k81*8);
      *(s8v*)&Bl[r0][k80*8] = *(const s8v*)(BT_ + (size_t)(nb+r0)*Kp + kt*32 + k80*8);
      *(s8v*)&Bl[r1][k81*8] = *(const s8v*)(BT_ + (size_t)(nb+r1)*Kp + kt*32 + k81*8);
    }
    __syncthreads();
    s8v af[4], bf[4];
    #pragma unroll
    for(int i=0;i<4;i++) af[i] = *(const s8v*)&Al[wm*64 + i*16 + lc][quad*8];
    #pragma unroll
    for(int j=0;j<4;j++) bf[j] = *(const s8v*)&Bl[wn*64 + j*16 + lc][quad*8];
    #pragma unroll
    for(int i=0;i<4;i++)
      #pragma unroll
      for(int j=0;j<4;j++)
        acc[i][j] = __builtin_amdgcn_mfma_f32_16x16x32_bf16(af[i], bf[j], acc[i][j],0,0,0);
  }
  #pragma unroll
  for(int j=0;j<4;j++){
    int col = nb + wn*64 + j*16 + lc;
    float bias = (col < G3) ? biasA[col] : biasB[col - G3];
    #pragma unroll
    for(int i=0;i<4;i++){
      int row0 = mb + wm*64 + i*16 + quad*4;
      #pragma unroll
      for(int r=0;r<4;r++)
        C[(size_t)(row0+r)*NTOT + col] = f2bf(acc[i][j][r] + bias);
    }
  }
}

// -------- zero the exchange counters (ws is re-poisoned before every launch) --
__global__ void zero_flags(u32* __restrict__ p){ p[threadIdx.x] = 0; }

// ---------------- GRU scan: column-split across 32 blocks ---------------------
// block = (dir, ug, bg): dir=blk&1, ug=(blk>>1)&3 (64-u slice), bg=blk>>3 (16 batches).
// rk slice (192 cols x 256 k, 98 KB) RESIDENT IN LDS — no register-allocator
// dependence (R4-R8 failure mode). Per step, the 4 ug-blocks of a (dir,bg)
// group exchange their 64-u h-slices through L3 via agent-scope atomics
// (cache-bypassing; per-XCD L2s are not coherent). Double-buffered slots +
// one counter per group; per-wave vmcnt(0) + block barrier before the
// counter increment gives release semantics without L2 writeback storms.
template<int MODE>
__global__ __launch_bounds__(256) void gru_scan2(
    const u16* __restrict__ xw,    // [BT,1536] bf16 (= X@K + b0, both dirs)
    const u16* __restrict__ rkT,   // [2][768][256] bf16 transposed recurrent kernels
    const float* __restrict__ bF, const float* __restrict__ bB,  // b[2][768] f32
    u16* __restrict__ h1out,       // MODE 0: [BT,512]
    float* __restrict__ h2out,     // MODE 1: [64,512] final states
    u64* __restrict__ xbuf,        // [2 slots][2 dir][4 bg][4 ug][256] u64
    u32* __restrict__ cnt)         // [2 dir][4 bg] stride 32 u32
{
  int blk = blockIdx.x;
  int dir = blk & 1, ug = (blk >> 1) & 3, bg = blk >> 3;
  int tid = threadIdx.x;
  int w = tid>>6, l = tid&63, lc = l&15, quad = l>>4;

  __shared__ u16 rks[NC][264];     // resident rk slice; row stride 528B -> conflict-free b128
  __shared__ u16 hfull[16][264];   // full h (all 256 u), single-buffered

  const u16*   rkd  = rkT + (size_t)dir*G3*U_DIM;
  const float* bias = (dir ? bB : bF) + G3;   // row 1 = recurrent bias

  for(int i=tid; i<16*264; i+=256) ((u16*)hfull)[i] = 0;
  // stage rk slice: 192 rows x 32 8-elem chunks
  for(int idx=tid; idx<NC*32; idx+=256){
    int row = idx>>5, c8 = idx&31;
    int ng = (row>>6)*256 + ug*64 + (row&63);   // global gate-col
    *(s8v*)&rks[row][c8*8] = *(const s8v*)(rkd + (size_t)ng*U_DIM + c8*8);
  }

  int ul  = w*16 + lc;          // local u (0..63)
  int ugl = ug*64 + ul;         // global u (0..255)
  float bg3[3];
  #pragma unroll
  for(int g=0;g<3;g++) bg3[g] = bias[g*256 + ugl];

  int t0 = dir ? (T_LEN-1) : 0;
  long tstride = dir ? -(long)NTOT      : (long)NTOT;
  long hstride = dir ? -(long)(2*U_DIM) : (long)(2*U_DIM);
  const u16* xwp[4];
  u16* hop[4];
  #pragma unroll
  for(int r=0;r<4;r++){
    int m = quad*4 + r;
    xwp[r] = xw + ((size_t)(bg*16+m)*T_LEN + t0)*NTOT + dir*G3 + ugl;
    hop[r] = (MODE==0) ? (h1out + ((size_t)(bg*16+m)*T_LEN + t0)*(2*U_DIM) + dir*U_DIM + ugl)
                       : nullptr;
  }

  u32* myc = cnt + (dir*4 + bg)*32;                 // padded counter
  u64* xgrp = xbuf + (size_t)(dir*4 + bg)*1024;     // group base (per slot: +slot*8192)

  __syncthreads();

  for(int step=0; step<T_LEN; step++){
    // xw preacts for this step (independent of h)
    u16 xu[3][4];
    #pragma unroll
    for(int r=0;r<4;r++)
      #pragma unroll
      for(int g=0;g<3;g++)
        xu[g][r] = xwp[r][g*256];

    // A-phase: read h(t) fragments + own h_prev
    s8v areg[8];
    #pragma unroll
    for(int kt=0;kt<8;kt++) areg[kt] = *(const s8v*)&hfull[lc][kt*32 + quad*8];
    float hp[4];
    #pragma unroll
    for(int r=0;r<4;r++) hp[r] = bf2f(hfull[quad*4+r][ugl]);
    __syncthreads();                       // all reads of h(t) done

    // MFMA: 3 gates x 8 ktiles, B from LDS
    f4v acc[3];
    #pragma unroll
    for(int g=0;g<3;g++) acc[g] = (f4v){0.f,0.f,0.f,0.f};
    #pragma unroll
    for(int kt=0;kt<8;kt++){
      #pragma unroll
      for(int g=0;g<3;g++){
        s8v b = *(const s8v*)&rks[g*64 + ul][kt*32 + quad*8];
        acc[g] = __builtin_amdgcn_mfma_f32_16x16x32_bf16(areg[kt], b, acc[g],0,0,0);
      }
    }

    // gates -> own 4 h-cells (batches quad*4..+3, col ugl)
    u16 hbf[4]; float hnf[4];
    #pragma unroll
    for(int r=0;r<4;r++){
      float zf = acc[0][r] + bg3[0] + bf2f(xu[0][r]);
      float rf = acc[1][r] + bg3[1] + bf2f(xu[1][r]);
      float rh = acc[2][r] + bg3[2];
      float xh = bf2f(xu[2][r]);
      zf = 1.f / (1.f + __expf(-zf));
      rf = 1.f / (1.f + __expf(-rf));
      float hc = xh + rf*rh;
      hc = fminf(fmaxf(hc, -15.f), 15.f);
      float e2 = __expf(2.f*hc);
      float th = (e2 - 1.f) / (e2 + 1.f);
      float hn = zf*hp[r] + (1.f - zf)*th;
      hnf[r] = hn;
      hbf[r] = f2bf(hn);
    }

    int slot = (step+1)&1;
    // publish own slice (cache-bypassing agent store; idx = ul*4+quad)
    u64 pk = (u64)hbf[0] | ((u64)hbf[1]<<16) | ((u64)hbf[2]<<32) | ((u64)hbf[3]<<48);
    __hip_atomic_store(&xgrp[(size_t)slot*8192 + ug*256 + ul*4 + quad], pk,
                       __ATOMIC_RELAXED, __HIP_MEMORY_SCOPE_AGENT);
    if(MODE==0){
      #pragma unroll
      for(int r=0;r<4;r++) hop[r][0] = hbf[r];
    } else if(step == T_LEN-1){
      #pragma unroll
      for(int r=0;r<4;r++)
        h2out[(size_t)(bg*16+quad*4+r)*(2*U_DIM) + dir*U_DIM + ugl] = hnf[r];
    }
    asm volatile("s_waitcnt vmcnt(0)" ::: "memory");   // own stores acked (per wave)
    // own slice into hfull
    #pragma unroll
    for(int r=0;r<4;r++) hfull[quad*4+r][ugl] = hbf[r];
    __syncthreads();                       // all waves' stores acked + own hfull done

    if(step < T_LEN-1){
      if(tid==0)
        __hip_atomic_fetch_add(myc, 1u, __ATOMIC_RELAXED, __HIP_MEMORY_SCOPE_AGENT);
      if(tid==0){
        u32 tgt = 4u*(u32)(step+1);
        while(__hip_atomic_load(myc, __ATOMIC_RELAXED, __HIP_MEMORY_SCOPE_AGENT) < tgt)
          __builtin_amdgcn_s_sleep(1);
      }
      __syncthreads();
      // peer slices: thread tid handles u64 idx=tid of each peer
      int uu = tid>>2, m4 = (tid&3)*4;
      #pragma unroll
      for(int j=1;j<4;j++){
        int pu = (ug+j)&3;
        u64 v = __hip_atomic_load(&xgrp[(size_t)slot*8192 + pu*256 + tid],
                                  __ATOMIC_RELAXED, __HIP_MEMORY_SCOPE_AGENT);
        #pragma unroll
        for(int i=0;i<4;i++)
          hfull[m4+i][pu*64+uu] = (u16)(v >> (16*i));
      }
      __syncthreads();                     // hfull = h(t+1) complete
    }

    #pragma unroll
    for(int r=0;r<4;r++){
      xwp[r] += tstride;
      if(MODE==0) hop[r] += hstride;
    }
  }
}

// ---------------- final projection + softmax (f32 output) ---------------------
__global__ void out_softmax(const float* __restrict__ h2, const float* __restrict__ wout,
                            const float* __restrict__ bout, float* __restrict__ out)
{
  __shared__ float lg[C_DIM];
  int b = blockIdx.x, l = threadIdx.x;   // 64 threads = 1 wave
  float acc[C_DIM];
  #pragma unroll
  for(int c=0;c<C_DIM;c++) acc[c] = 0.f;
  for(int k=l; k<2*U_DIM; k+=64){
    float hv = h2[b*2*U_DIM + k];
    #pragma unroll
    for(int c=0;c<C_DIM;c++) acc[c] += hv * wout[k*C_DIM + c];
  }
  #pragma unroll
  for(int c=0;c<C_DIM;c++){
    float v = acc[c];
    for(int off=32; off; off>>=1) v += __shfl_down(v, off);
    if(l==0) lg[c] = v + bout[c];
  }
  __syncthreads();
  if(l==0){
    float mx = lg[0];
    for(int c=1;c<C_DIM;c++) mx = fmaxf(mx, lg[c]);
    float sum = 0.f, ex[C_DIM];
    for(int c=0;c<C_DIM;c++){ ex[c] = __expf(lg[c]-mx); sum += ex[c]; }
    for(int c=0;c<C_DIM;c++) out[b*C_DIM + c] = ex[c]/sum;
  }
}

extern "C" void kernel_launch(void* const* d_in, const int* in_sizes, int n_in,
                              void* d_out, int out_size, void* d_ws, size_t ws_size,
                              hipStream_t stream)
{
  const int*   x    = (const int*)d_in[0];
  const float* emb  = (const float*)d_in[1];
  const float* k1f  = (const float*)d_in[2];
  const float* rk1f = (const float*)d_in[3];
  const float* b1f  = (const float*)d_in[4];
  const float* k1b  = (const float*)d_in[5];
  const float* rk1b = (const float*)d_in[6];
  const float* b1b  = (const float*)d_in[7];
  const float* k2f  = (const float*)d_in[8];
  const float* rk2f = (const float*)d_in[9];
  const float* b2f  = (const float*)d_in[10];
  const float* k2b  = (const float*)d_in[11];
  const float* rk2b = (const float*)d_in[12];
  const float* b2b  = (const float*)d_in[13];
  const float* wout = (const float*)d_in[14];
  const float* bout = (const float*)d_in[15];

  char* ws = (char*)d_ws;
  u16*  k1t   = (u16*)(ws);                       // 983,040 B     [1536,320]
  u16*  k2t   = (u16*)(ws + 983040);              // 1,572,864 B   [1536,512]
  u16*  rkt   = (u16*)(ws + 2555904);             // 1,572,864 B   4x[768,256]
  float* h2   = (float*)(ws + 4128768);           // 131,072 B     [64,512]
  u16*  h1    = (u16*)(ws + 4259840);             // 33,554,432 B  [BT,512]
  u16*  e_pad = (u16*)(ws + 4259840);             // (alias h1)
  u16*  xwb   = (u16*)(ws + 37814272);            // 100,663,296 B [BT,1536]
  u64*  xbuf  = (u64*)(ws + 138477568);           // 131,072 B     exchange slots
  u32*  cnt   = (u32*)(ws + 138608640);           // 2,048 B       2 layers x 8 counters x 32
  u32*  cnt2  = cnt + 256;

  zero_flags<<<1,512,0,stream>>>(cnt);

  transpose_cc<<<(NTOT*EP +255)/256,256,0,stream>>>(k1f, k1b, k1t, E_DIM, EP, NTOT);
  transpose_cc<<<(NTOT*512+255)/256,256,0,stream>>>(k2f, k2b, k2t, 512, 512, NTOT);
  transpose_cc<<<(G3*U_DIM+255)/256,256,0,stream>>>(rk1f, rk1f, rkt,                U_DIM, U_DIM, G3);
  transpose_cc<<<(G3*U_DIM+255)/256,256,0,stream>>>(rk1b, rk1b, rkt + 1*G3*U_DIM,   U_DIM, U_DIM, G3);
  transpose_cc<<<(G3*U_DIM+255)/256,256,0,stream>>>(rk2f, rk2f, rkt + 2*G3*U_DIM,   U_DIM, U_DIM, G3);
  transpose_cc<<<(G3*U_DIM+255)/256,256,0,stream>>>(rk2b, rk2b, rkt + 3*G3*U_DIM,   U_DIM, U_DIM, G3);

  embed_pad<<<(BT*EP)/256,256,0,stream>>>(x, emb, e_pad);

  // layer 1: xw = e @ K1 + b0 ; scan -> h1
  gemm_bt<<<dim3(12,256),256,0,stream>>>(e_pad, k1t, xwb, EP, b1f, b1b);
  gru_scan2<0><<<32,256,0,stream>>>(xwb, rkt, b1f, b1b, h1, nullptr, xbuf, cnt);

  // layer 2: xw = h1 @ K2 + b0 ; scan -> h2 (final states only)
  gemm_bt<<<dim3(12,256),256,0,stream>>>(h1, k2t, xwb, 512, b2f, b2b);
  gru_scan2<1><<<32,256,0,stream>>>(xwb, rkt + 2*G3*U_DIM, b2f, b2b, nullptr, h2, xbuf, cnt2);

  out_softmax<<<64,64,0,stream>>>(h2, wout, bout, (float*)d_out);
}

// Round 11
// 3273.993 us; speedup vs baseline: 1.2175x; 1.1457x over previous
//
#include <hip/hip_runtime.h>

typedef unsigned short u16;
typedef unsigned int   u32;
typedef __attribute__((ext_vector_type(8))) short s8v;   // 8 x bf16 bits (4 VGPRs)
typedef __attribute__((ext_vector_type(4))) float f4v;   // MFMA accumulator
typedef __attribute__((ext_vector_type(4))) int   i4v;   // 4 VGPRs (generic 16B)

#define B_SZ  64
#define T_LEN 512
#define U_DIM 256
#define E_DIM 300
#define EP    320          // E padded to multiple of 32
#define G3    768          // 3*U
#define NTOT  1536         // both directions concatenated
#define C_DIM 20
#define BT    (B_SZ*T_LEN)

__device__ __forceinline__ float bf2f(u16 h){ return __uint_as_float(((u32)h)<<16); }
__device__ __forceinline__ u16 f2bf(float f){
  u32 u = __float_as_uint(f);
  u32 r = (u + 0x7FFFu + ((u>>16)&1u)) >> 16;   // RNE
  return (u16)r;
}

// ------------- embedding gather f32 -> bf16, K-pad (300 -> 320, zeros) --------
__global__ void embed_pad(const int* __restrict__ x, const float* __restrict__ emb,
                          u16* __restrict__ e){
  int idx = blockIdx.x*256 + threadIdx.x;
  if(idx >= BT*EP) return;
  int row = idx / EP, col = idx - row*EP;
  u16 v = 0;
  if(col < E_DIM) v = f2bf(emb[(size_t)x[row]*E_DIM + col]);
  e[idx] = v;
}

// ------ transpose + concat two f32 [K,768] sources -> bf16 dst[N][Kp] ---------
__global__ void transpose_cc(const float* __restrict__ A, const float* __restrict__ Bm,
                             u16* __restrict__ dst, int K, int Kp, int N){
  int idx = blockIdx.x*256 + threadIdx.x;
  if(idx >= N*Kp) return;
  int n = idx / Kp, k = idx - n*Kp;
  u16 v = 0;
  if(k < K){
    const float* s = (n < G3) ? A : Bm;
    int nn = (n < G3) ? n : n - G3;
    v = f2bf(s[(size_t)k*G3 + nn]);
  }
  dst[idx] = v;
}

// ---------------- GEMM: C[M,1536] = A[M,Kp] @ BT^T + bias (bf16 out) ----------
__global__ __launch_bounds__(256) void gemm_bt(
    const u16* __restrict__ A, const u16* __restrict__ BT_, u16* __restrict__ C,
    int Kp, const float* __restrict__ biasA, const float* __restrict__ biasB)
{
  __shared__ u16 Al[128][40];   // +8 pad breaks bank collisions
  __shared__ u16 Bl[128][40];
  int tid = threadIdx.x;
  int w = tid>>6, l = tid&63, lc = l&15, quad = l>>4;
  int wm = w>>1, wn = w&1;
  int mb = blockIdx.y*128, nb = blockIdx.x*128;

  f4v acc[4][4];
  #pragma unroll
  for(int i=0;i<4;i++)
    #pragma unroll
    for(int j=0;j<4;j++) acc[i][j] = (f4v){0.f,0.f,0.f,0.f};

  int nk = Kp >> 5;
  for(int kt=0; kt<nk; kt++){
    __syncthreads();
    {
      int c0 = tid, c1 = tid + 256;
      int r0 = c0>>2, k80 = c0&3;
      int r1 = c1>>2, k81 = c1&3;
      *(s8v*)&Al[r0][k80*8] = *(const s8v*)(A   + (size_t)(mb+r0)*Kp + kt*32 + k80*8);
      *(s8v*)&Al[r1][k81*8] = *(const s8v*)(A   + (size_t)(mb+r1)*Kp + kt*32 + k81*8);
      *(s8v*)&Bl[r0][k80*8] = *(const s8v*)(BT_ + (size_t)(nb+r0)*Kp + kt*32 + k80*8);
      *(s8v*)&Bl[r1][k81*8] = *(const s8v*)(BT_ + (size_t)(nb+r1)*Kp + kt*32 + k81*8);
    }
    __syncthreads();
    s8v af[4], bf[4];
    #pragma unroll
    for(int i=0;i<4;i++) af[i] = *(const s8v*)&Al[wm*64 + i*16 + lc][quad*8];
    #pragma unroll
    for(int j=0;j<4;j++) bf[j] = *(const s8v*)&Bl[wn*64 + j*16 + lc][quad*8];
    #pragma unroll
    for(int i=0;i<4;i++)
      #pragma unroll
      for(int j=0;j<4;j++)
        acc[i][j] = __builtin_amdgcn_mfma_f32_16x16x32_bf16(af[i], bf[j], acc[i][j],0,0,0);
  }
  #pragma unroll
  for(int j=0;j<4;j++){
    int col = nb + wn*64 + j*16 + lc;
    float bias = (col < G3) ? biasA[col] : biasB[col - G3];
    #pragma unroll
    for(int i=0;i<4;i++){
      int row0 = mb + wm*64 + i*16 + quad*4;
      #pragma unroll
      for(int r=0;r<4;r++)
        C[(size_t)(row0+r)*NTOT + col] = f2bf(acc[i][j][r] + bias);
    }
  }
}

// ---------------- GRU scan: hard-coded AGPR + LDS residency (v2) --------------
// 8 blocks (dir = blk&1, bg = blk>>1, M=16). 512 threads = 8 waves; wave w owns
// u in [32w,32w+32) -> 96 gate-cols.
//   ktiles 3..7 (160 k): a0..a119, written once via explicit v_accvgpr_write.
//   ktiles 0..2 (96 k): LDS, wave-private fragment order (lane-contiguous 16B).
// R10 NaN root cause: intrinsic MFMAs in the loop carried AGPR-class acc vregs
// that RA homed in a0..a119 between clobber points. v2: ZERO intrinsic MFMAs in
// the loop — all 48 are asm with "v"-only constraints (no AGPR-class values
// exist). Hazards handled manually: first MFMA per chain uses inline C=0 (no
// VALU-init hazard); last MFMA per chain carries s_nop 7 x2 (MFMA->VALU drain);
// MFMA->MFMA same-D chains need 0 waits; ds_read waits are operand-based.

#define INITF(F,A0,A1,A2,A3) { \
  i4v t = *(const i4v*)(rkd + (size_t)((F/10)*256 + w*32 + ((F/5)&1)*16 + lc)*U_DIM \
                            + ((F%5)+3)*32 + quad*8); \
  asm volatile("v_accvgpr_write_b32 a" #A0 ", %0\n\t" \
               "v_accvgpr_write_b32 a" #A1 ", %1\n\t" \
               "v_accvgpr_write_b32 a" #A2 ", %2\n\t" \
               "v_accvgpr_write_b32 a" #A3 ", %3" \
               :: "v"(t[0]), "v"(t[1]), "v"(t[2]), "v"(t[3]) \
               : "a" #A0, "a" #A1, "a" #A2, "a" #A3); }

// first in chain: D = A*B + 0 (inline const C — no init, no VALU->MFMA hazard)
#define MFZ(ACC,AF,BF) \
  asm("v_mfma_f32_16x16x32_bf16 %0, %1, %2, 0" : "=&v"(ACC) : "v"(AF), "v"(BF))
// middle, B in AGPR (hard-coded range)
#define MFA(ACC,AF,R0,R3) \
  asm("v_mfma_f32_16x16x32_bf16 %0, %1, a[" #R0 ":" #R3 "], %0" \
      : "+v"(ACC) : "v"(AF))
// middle, B in VGPR (from LDS)
#define MFV(ACC,AF,BF) \
  asm("v_mfma_f32_16x16x32_bf16 %0, %1, %2, %0" : "+v"(ACC) : "v"(AF), "v"(BF))
// last in chain: trailing drain nops so following VALU reads of ACC are safe
#define MFE(ACC,AF,BF) \
  asm("v_mfma_f32_16x16x32_bf16 %0, %1, %2, %0\n\ts_nop 7\n\ts_nop 7" \
      : "+v"(ACC) : "v"(AF), "v"(BF))

#define AFENCE asm volatile("" ::: \
  "a0","a1","a2","a3","a4","a5","a6","a7","a8","a9", \
  "a10","a11","a12","a13","a14","a15","a16","a17","a18","a19", \
  "a20","a21","a22","a23","a24","a25","a26","a27","a28","a29", \
  "a30","a31","a32","a33","a34","a35","a36","a37","a38","a39", \
  "a40","a41","a42","a43","a44","a45","a46","a47","a48","a49", \
  "a50","a51","a52","a53","a54","a55","a56","a57","a58","a59", \
  "a60","a61","a62","a63","a64","a65","a66","a67","a68","a69", \
  "a70","a71","a72","a73","a74","a75","a76","a77","a78","a79", \
  "a80","a81","a82","a83","a84","a85","a86","a87","a88","a89", \
  "a90","a91","a92","a93","a94","a95","a96","a97","a98","a99", \
  "a100","a101","a102","a103","a104","a105","a106","a107","a108","a109", \
  "a110","a111","a112","a113","a114","a115","a116","a117","a118","a119")

template<int MODE>
__global__ __launch_bounds__(512,2) void gru_scan3(
    const u16* __restrict__ xw,    // [BT,1536] bf16 (= X@K + b0, both dirs)
    const u16* __restrict__ rkT,   // [2][768][256] bf16 transposed recurrent kernels
    const float* __restrict__ bF, const float* __restrict__ bB,  // b[2][768] f32
    u16* __restrict__ h1out,       // MODE 0: [BT,512]
    float* __restrict__ h2out)     // MODE 1: [64,512] final states
{
  int dir = blockIdx.x & 1, bg = blockIdx.x >> 1;
  int b0 = bg*16;
  int tid = threadIdx.x;
  int w = tid>>6, l = tid&63, lc = l&15, quad = l>>4;

  __shared__ u16 rklW[8*18*64*8];  // wave-private B-frags, ktiles 0..2 (147,456 B)
  __shared__ u16 hb[16][264];      // h state (single buffer, 2 barriers/step)
  for(int i=tid; i<16*264; i+=512) ((u16*)hb)[i] = 0;

  const u16*   rkd  = rkT + (size_t)dir*G3*U_DIM;
  const float* bias = (dir ? bB : bF) + G3;   // row 1 = recurrent bias

  // stage LDS B-frags: frag fi=(g*2+s)*3+kt for wave w2, lane-contiguous 16B
  for(int idx=tid; idx<8*18*64; idx+=512){
    int w2 = idx/1152, r = idx%1152, fi = r>>6, lane = r&63;
    int gs = fi/3, kt = fi%3;
    int n  = (gs>>1)*256 + w2*32 + (gs&1)*16 + (lane&15);
    *(s8v*)&rklW[(size_t)idx*8] =
      *(const s8v*)(rkd + (size_t)n*U_DIM + kt*32 + (lane>>4)*8);
  }

  // AGPR-resident frags: F=(g*2+s)*5+(kt-3) -> a[4F:4F+3]
  INITF(0,0,1,2,3)       INITF(1,4,5,6,7)       INITF(2,8,9,10,11)
  INITF(3,12,13,14,15)   INITF(4,16,17,18,19)   INITF(5,20,21,22,23)
  INITF(6,24,25,26,27)   INITF(7,28,29,30,31)   INITF(8,32,33,34,35)
  INITF(9,36,37,38,39)   INITF(10,40,41,42,43)  INITF(11,44,45,46,47)
  INITF(12,48,49,50,51)  INITF(13,52,53,54,55)  INITF(14,56,57,58,59)
  INITF(15,60,61,62,63)  INITF(16,64,65,66,67)  INITF(17,68,69,70,71)
  INITF(18,72,73,74,75)  INITF(19,76,77,78,79)  INITF(20,80,81,82,83)
  INITF(21,84,85,86,87)  INITF(22,88,89,90,91)  INITF(23,92,93,94,95)
  INITF(24,96,97,98,99)  INITF(25,100,101,102,103) INITF(26,104,105,106,107)
  INITF(27,108,109,110,111) INITF(28,112,113,114,115) INITF(29,116,117,118,119)

  float bgf[3][2];
  #pragma unroll
  for(int g=0;g<3;g++)
    #pragma unroll
    for(int s=0;s<2;s++)
      bgf[g][s] = bias[g*256 + w*32 + s*16 + lc];

  int t0 = dir ? (T_LEN-1) : 0;
  long tstride = dir ? -(long)NTOT      : (long)NTOT;
  long hstride = dir ? -(long)(2*U_DIM) : (long)(2*U_DIM);
  const u16* xwp[4];
  u16* hop[4];
  #pragma unroll
  for(int r=0;r<4;r++){
    int m = quad*4 + r;
    xwp[r] = xw + ((size_t)(b0+m)*T_LEN + t0)*NTOT + dir*G3 + w*32 + lc;
    hop[r] = (MODE==0) ? (h1out + ((size_t)(b0+m)*T_LEN + t0)*(2*U_DIM) + dir*U_DIM + w*32 + lc)
                       : nullptr;
  }

  __syncthreads();

  for(int step=0; step<T_LEN; step++){
    AFENCE;   // block cross-iteration compiler use/spill into a0..a119

    // xw preacts (independent of h)
    u16 xu[3][2][4];
    #pragma unroll
    for(int r=0;r<4;r++)
      #pragma unroll
      for(int g=0;g<3;g++)
        #pragma unroll
        for(int s=0;s<2;s++)
          xu[g][s][r] = xwp[r][g*256 + s*16];

    // phase 1: all reads of h(t)
    s8v areg[8];
    #pragma unroll
    for(int kt=0;kt<8;kt++) areg[kt] = *(const s8v*)&hb[lc][kt*32 + quad*8];
    float hp[2][4];
    #pragma unroll
    for(int s=0;s<2;s++)
      #pragma unroll
      for(int r=0;r<4;r++)
        hp[s][r] = bf2f(hb[quad*4+r][w*32 + s*16 + lc]);
    __syncthreads();

    f4v acc[3][2];
    s8v bl[6];
    // kt0 (asm, LDS B, inline C=0)
    #pragma unroll
    for(int g=0;g<3;g++)
      #pragma unroll
      for(int s=0;s<2;s++)
        bl[g*2+s] = *(const s8v*)&rklW[(size_t)((w*18+(g*2+s)*3)*64 + l)*8];
    MFZ(acc[0][0],areg[0],bl[0]);  MFZ(acc[0][1],areg[0],bl[1]);
    MFZ(acc[1][0],areg[0],bl[2]);  MFZ(acc[1][1],areg[0],bl[3]);
    MFZ(acc[2][0],areg[0],bl[4]);  MFZ(acc[2][1],areg[0],bl[5]);
    // kt3..7 (asm, AGPR B)
    MFA(acc[0][0],areg[3],0,3);    MFA(acc[0][1],areg[3],20,23);
    MFA(acc[1][0],areg[3],40,43);  MFA(acc[1][1],areg[3],60,63);
    MFA(acc[2][0],areg[3],80,83);  MFA(acc[2][1],areg[3],100,103);
    MFA(acc[0][0],areg[4],4,7);    MFA(acc[0][1],areg[4],24,27);
    MFA(acc[1][0],areg[4],44,47);  MFA(acc[1][1],areg[4],64,67);
    MFA(acc[2][0],areg[4],84,87);  MFA(acc[2][1],areg[4],104,107);
    MFA(acc[0][0],areg[5],8,11);   MFA(acc[0][1],areg[5],28,31);
    MFA(acc[1][0],areg[5],48,51);  MFA(acc[1][1],areg[5],68,71);
    MFA(acc[2][0],areg[5],88,91);  MFA(acc[2][1],areg[5],108,111);
    MFA(acc[0][0],areg[6],12,15);  MFA(acc[0][1],areg[6],32,35);
    MFA(acc[1][0],areg[6],52,55);  MFA(acc[1][1],areg[6],72,75);
    MFA(acc[2][0],areg[6],92,95);  MFA(acc[2][1],areg[6],112,115);
    MFA(acc[0][0],areg[7],16,19);  MFA(acc[0][1],areg[7],36,39);
    MFA(acc[1][0],areg[7],56,59);  MFA(acc[1][1],areg[7],76,79);
    MFA(acc[2][0],areg[7],96,99);  MFA(acc[2][1],areg[7],116,119);
    // kt1 (asm, LDS B)
    #pragma unroll
    for(int g=0;g<3;g++)
      #pragma unroll
      for(int s=0;s<2;s++)
        bl[g*2+s] = *(const s8v*)&rklW[(size_t)((w*18+(g*2+s)*3+1)*64 + l)*8];
    MFV(acc[0][0],areg[1],bl[0]);  MFV(acc[0][1],areg[1],bl[1]);
    MFV(acc[1][0],areg[1],bl[2]);  MFV(acc[1][1],areg[1],bl[3]);
    MFV(acc[2][0],areg[1],bl[4]);  MFV(acc[2][1],areg[1],bl[5]);
    // kt2 (asm, LDS B, trailing drain nops)
    #pragma unroll
    for(int g=0;g<3;g++)
      #pragma unroll
      for(int s=0;s<2;s++)
        bl[g*2+s] = *(const s8v*)&rklW[(size_t)((w*18+(g*2+s)*3+2)*64 + l)*8];
    MFE(acc[0][0],areg[2],bl[0]);  MFE(acc[0][1],areg[2],bl[1]);
    MFE(acc[1][0],areg[2],bl[2]);  MFE(acc[1][1],areg[2],bl[3]);
    MFE(acc[2][0],areg[2],bl[4]);  MFE(acc[2][1],areg[2],bl[5]);

    AFENCE;   // block gate-section spills from using a0..a119

    // gates + state update
    #pragma unroll
    for(int s=0;s<2;s++){
      int u = w*32 + s*16 + lc;
      #pragma unroll
      for(int r=0;r<4;r++){
        int m = quad*4 + r;
        float zf = acc[0][s][r] + bgf[0][s] + bf2f(xu[0][s][r]);
        float rf = acc[1][s][r] + bgf[1][s] + bf2f(xu[1][s][r]);
        float rh = acc[2][s][r] + bgf[2][s];
        float xh = bf2f(xu[2][s][r]);
        zf = 1.f / (1.f + __expf(-zf));
        rf = 1.f / (1.f + __expf(-rf));
        float hc = xh + rf*rh;
        hc = fminf(fmaxf(hc, -15.f), 15.f);
        float e2 = __expf(2.f*hc);
        float th = (e2 - 1.f) / (e2 + 1.f);
        float hn = zf*hp[s][r] + (1.f - zf)*th;
        u16 hbf = f2bf(hn);
        hb[m][u] = hbf;
        if(MODE == 0)
          hop[r][s*16] = hbf;
        else if(step == T_LEN-1)
          h2out[(size_t)(b0+m)*(2*U_DIM) + dir*U_DIM + u] = hn;
      }
    }

    #pragma unroll
    for(int r=0;r<4;r++){
      xwp[r] += tstride;
      if(MODE==0) hop[r] += hstride;
    }
    __syncthreads();
  }
}

// ---------------- final projection + softmax (f32 output) ---------------------
__global__ void out_softmax(const float* __restrict__ h2, const float* __restrict__ wout,
                            const float* __restrict__ bout, float* __restrict__ out)
{
  __shared__ float lg[C_DIM];
  int b = blockIdx.x, l = threadIdx.x;   // 64 threads = 1 wave
  float acc[C_DIM];
  #pragma unroll
  for(int c=0;c<C_DIM;c++) acc[c] = 0.f;
  for(int k=l; k<2*U_DIM; k+=64){
    float hv = h2[b*2*U_DIM + k];
    #pragma unroll
    for(int c=0;c<C_DIM;c++) acc[c] += hv * wout[k*C_DIM + c];
  }
  #pragma unroll
  for(int c=0;c<C_DIM;c++){
    float v = acc[c];
    for(int off=32; off; off>>=1) v += __shfl_down(v, off);
    if(l==0) lg[c] = v + bout[c];
  }
  __syncthreads();
  if(l==0){
    float mx = lg[0];
    for(int c=1;c<C_DIM;c++) mx = fmaxf(mx, lg[c]);
    float sum = 0.f, ex[C_DIM];
    for(int c=0;c<C_DIM;c++){ ex[c] = __expf(lg[c]-mx); sum += ex[c]; }
    for(int c=0;c<C_DIM;c++) out[b*C_DIM + c] = ex[c]/sum;
  }
}

extern "C" void kernel_launch(void* const* d_in, const int* in_sizes, int n_in,
                              void* d_out, int out_size, void* d_ws, size_t ws_size,
                              hipStream_t stream)
{
  const int*   x    = (const int*)d_in[0];
  const float* emb  = (const float*)d_in[1];
  const float* k1f  = (const float*)d_in[2];
  const float* rk1f = (const float*)d_in[3];
  const float* b1f  = (const float*)d_in[4];
  const float* k1b  = (const float*)d_in[5];
  const float* rk1b = (const float*)d_in[6];
  const float* b1b  = (const float*)d_in[7];
  const float* k2f  = (const float*)d_in[8];
  const float* rk2f = (const float*)d_in[9];
  const float* b2f  = (const float*)d_in[10];
  const float* k2b  = (const float*)d_in[11];
  const float* rk2b = (const float*)d_in[12];
  const float* b2b  = (const float*)d_in[13];
  const float* wout = (const float*)d_in[14];
  const float* bout = (const float*)d_in[15];

  char* ws = (char*)d_ws;
  u16*  k1t   = (u16*)(ws);                       // 983,040 B     [1536,320]
  u16*  k2t   = (u16*)(ws + 983040);              // 1,572,864 B   [1536,512]
  u16*  rkt   = (u16*)(ws + 2555904);             // 1,572,864 B   4x[768,256]
  float* h2   = (float*)(ws + 4128768);           // 131,072 B     [64,512]
  u16*  h1    = (u16*)(ws + 4259840);             // 33,554,432 B  [BT,512]
  u16*  e_pad = (u16*)(ws + 4259840);             // (alias h1)
  u16*  xwb   = (u16*)(ws + 37814272);            // 100,663,296 B [BT,1536]

  transpose_cc<<<(NTOT*EP +255)/256,256,0,stream>>>(k1f, k1b, k1t, E_DIM, EP, NTOT);
  transpose_cc<<<(NTOT*512+255)/256,256,0,stream>>>(k2f, k2b, k2t, 512, 512, NTOT);
  transpose_cc<<<(G3*U_DIM+255)/256,256,0,stream>>>(rk1f, rk1f, rkt,                U_DIM, U_DIM, G3);
  transpose_cc<<<(G3*U_DIM+255)/256,256,0,stream>>>(rk1b, rk1b, rkt + 1*G3*U_DIM,   U_DIM, U_DIM, G3);
  transpose_cc<<<(G3*U_DIM+255)/256,256,0,stream>>>(rk2f, rk2f, rkt + 2*G3*U_DIM,   U_DIM, U_DIM, G3);
  transpose_cc<<<(G3*U_DIM+255)/256,256,0,stream>>>(rk2b, rk2b, rkt + 3*G3*U_DIM,   U_DIM, U_DIM, G3);

  embed_pad<<<(BT*EP)/256,256,0,stream>>>(x, emb, e_pad);

  // layer 1: xw = e @ K1 + b0 ; scan -> h1
  gemm_bt<<<dim3(12,256),256,0,stream>>>(e_pad, k1t, xwb, EP, b1f, b1b);
  gru_scan3<0><<<8,512,0,stream>>>(xwb, rkt, b1f, b1b, h1, nullptr);

  // layer 2: xw = h1 @ K2 + b0 ; scan -> h2 (final states only)
  gemm_bt<<<dim3(12,256),256,0,stream>>>(h1, k2t, xwb, 512, b2f, b2b);
  gru_scan3<1><<<8,512,0,stream>>>(xwb, rkt + 2*G3*U_DIM, b2f, b2b, nullptr, h2);

  out_softmax<<<64,64,0,stream>>>(h2, wout, bout, (float*)d_out);
}

// Round 12
// 2859.568 us; speedup vs baseline: 1.3940x; 1.1449x over previous
//
#include <hip/hip_runtime.h>

typedef unsigned short u16;
typedef unsigned int   u32;
typedef __attribute__((ext_vector_type(8))) short s8v;   // 8 x bf16 bits (4 VGPRs)
typedef __attribute__((ext_vector_type(4))) float f4v;   // MFMA accumulator
typedef __attribute__((ext_vector_type(4))) int   i4v;   // 4 VGPRs (generic 16B)

#define B_SZ  64
#define T_LEN 512
#define U_DIM 256
#define E_DIM 300
#define EP    320          // E padded to multiple of 32
#define G3    768          // 3*U
#define NTOT  1536         // both directions concatenated
#define C_DIM 20
#define BT    (B_SZ*T_LEN)

__device__ __forceinline__ float bf2f(u16 h){ return __uint_as_float(((u32)h)<<16); }
__device__ __forceinline__ u16 f2bf(float f){
  u32 u = __float_as_uint(f);
  u32 r = (u + 0x7FFFu + ((u>>16)&1u)) >> 16;   // RNE
  return (u16)r;
}

// ------------- embedding gather f32 -> bf16, K-pad (300 -> 320, zeros) --------
__global__ void embed_pad(const int* __restrict__ x, const float* __restrict__ emb,
                          u16* __restrict__ e){
  int idx = blockIdx.x*256 + threadIdx.x;
  if(idx >= BT*EP) return;
  int row = idx / EP, col = idx - row*EP;
  u16 v = 0;
  if(col < E_DIM) v = f2bf(emb[(size_t)x[row]*E_DIM + col]);
  e[idx] = v;
}

// ------ transpose + concat two f32 [K,768] sources -> bf16 dst[N][Kp] ---------
__global__ void transpose_cc(const float* __restrict__ A, const float* __restrict__ Bm,
                             u16* __restrict__ dst, int K, int Kp, int N){
  int idx = blockIdx.x*256 + threadIdx.x;
  if(idx >= N*Kp) return;
  int n = idx / Kp, k = idx - n*Kp;
  u16 v = 0;
  if(k < K){
    const float* s = (n < G3) ? A : Bm;
    int nn = (n < G3) ? n : n - G3;
    v = f2bf(s[(size_t)k*G3 + nn]);
  }
  dst[idx] = v;
}

// ---------------- GEMM: C[M,1536] = A[M,Kp] @ BT^T + bias (bf16 out) ----------
__global__ __launch_bounds__(256) void gemm_bt(
    const u16* __restrict__ A, const u16* __restrict__ BT_, u16* __restrict__ C,
    int Kp, const float* __restrict__ biasA, const float* __restrict__ biasB)
{
  __shared__ u16 Al[128][40];   // +8 pad breaks bank collisions
  __shared__ u16 Bl[128][40];
  int tid = threadIdx.x;
  int w = tid>>6, l = tid&63, lc = l&15, quad = l>>4;
  int wm = w>>1, wn = w&1;
  int mb = blockIdx.y*128, nb = blockIdx.x*128;

  f4v acc[4][4];
  #pragma unroll
  for(int i=0;i<4;i++)
    #pragma unroll
    for(int j=0;j<4;j++) acc[i][j] = (f4v){0.f,0.f,0.f,0.f};

  int nk = Kp >> 5;
  for(int kt=0; kt<nk; kt++){
    __syncthreads();
    {
      int c0 = tid, c1 = tid + 256;
      int r0 = c0>>2, k80 = c0&3;
      int r1 = c1>>2, k81 = c1&3;
      *(s8v*)&Al[r0][k80*8] = *(const s8v*)(A   + (size_t)(mb+r0)*Kp + kt*32 + k80*8);
      *(s8v*)&Al[r1][k81*8] = *(const s8v*)(A   + (size_t)(mb+r1)*Kp + kt*32 + k81*8);
      *(s8v*)&Bl[r0][k80*8] = *(const s8v*)(BT_ + (size_t)(nb+r0)*Kp + kt*32 + k80*8);
      *(s8v*)&Bl[r1][k81*8] = *(const s8v*)(BT_ + (size_t)(nb+r1)*Kp + kt*32 + k81*8);
    }
    __syncthreads();
    s8v af[4], bf[4];
    #pragma unroll
    for(int i=0;i<4;i++) af[i] = *(const s8v*)&Al[wm*64 + i*16 + lc][quad*8];
    #pragma unroll
    for(int j=0;j<4;j++) bf[j] = *(const s8v*)&Bl[wn*64 + j*16 + lc][quad*8];
    #pragma unroll
    for(int i=0;i<4;i++)
      #pragma unroll
      for(int j=0;j<4;j++)
        acc[i][j] = __builtin_amdgcn_mfma_f32_16x16x32_bf16(af[i], bf[j], acc[i][j],0,0,0);
  }
  #pragma unroll
  for(int j=0;j<4;j++){
    int col = nb + wn*64 + j*16 + lc;
    float bias = (col < G3) ? biasA[col] : biasB[col - G3];
    #pragma unroll
    for(int i=0;i<4;i++){
      int row0 = mb + wm*64 + i*16 + quad*4;
      #pragma unroll
      for(int r=0;r<4;r++)
        C[(size_t)(row0+r)*NTOT + col] = f2bf(acc[i][j][r] + bias);
    }
  }
}

// ---------------- GRU scan: hard-coded AGPR + LDS residency (v3) --------------
// 8 blocks (dir = blk&1, bg = blk>>1, M=16). 512 threads = 8 waves; wave w owns
// u in [32w,32w+32) -> 96 gate-cols.
//   AGPR (128/128): kt3..7 all gs -> a0..a119 (F=gs*5+(kt-3), a[4F:4F+3]);
//                   kt1 gs0 -> a120..123, kt1 gs1 -> a124..127.
//   LDS: remaining 16 frags/wave, wave-private lane-contiguous 16B.
// v3 changes vs R11: double-buffered hb + ONE custom barrier per step
// (s_waitcnt lgkmcnt(0); s_barrier — no vmcnt drain of xu loads / h1 stores),
// areg staged in halves (arch-VGPR pressure < 128, no in-loop spills),
// cheaper gates (v_rcp sigmoid/tanh, no clamp).

#define INITF(F,A0,A1,A2,A3) { \
  i4v t = *(const i4v*)(rkd + (size_t)((F/10)*256 + w*32 + ((F/5)&1)*16 + lc)*U_DIM \
                            + ((F%5)+3)*32 + quad*8); \
  asm volatile("v_accvgpr_write_b32 a" #A0 ", %0\n\t" \
               "v_accvgpr_write_b32 a" #A1 ", %1\n\t" \
               "v_accvgpr_write_b32 a" #A2 ", %2\n\t" \
               "v_accvgpr_write_b32 a" #A3 ", %3" \
               :: "v"(t[0]), "v"(t[1]), "v"(t[2]), "v"(t[3]) \
               : "a" #A0, "a" #A1, "a" #A2, "a" #A3); }

// explicit-col variant (for the two kt=1 frags in a120..127)
#define INITX(NOFF,KT,A0,A1,A2,A3) { \
  i4v t = *(const i4v*)(rkd + (size_t)(NOFF)*U_DIM + (KT)*32 + quad*8); \
  asm volatile("v_accvgpr_write_b32 a" #A0 ", %0\n\t" \
               "v_accvgpr_write_b32 a" #A1 ", %1\n\t" \
               "v_accvgpr_write_b32 a" #A2 ", %2\n\t" \
               "v_accvgpr_write_b32 a" #A3 ", %3" \
               :: "v"(t[0]), "v"(t[1]), "v"(t[2]), "v"(t[3]) \
               : "a" #A0, "a" #A1, "a" #A2, "a" #A3); }

#define MFZ(ACC,AF,BF) \
  asm("v_mfma_f32_16x16x32_bf16 %0, %1, %2, 0" : "=&v"(ACC) : "v"(AF), "v"(BF))
#define MFA(ACC,AF,R0,R3) \
  asm("v_mfma_f32_16x16x32_bf16 %0, %1, a[" #R0 ":" #R3 "], %0" \
      : "+v"(ACC) : "v"(AF))
#define MFV(ACC,AF,BF) \
  asm("v_mfma_f32_16x16x32_bf16 %0, %1, %2, %0" : "+v"(ACC) : "v"(AF), "v"(BF))
#define MFAE(ACC,AF,R0,R3) \
  asm("v_mfma_f32_16x16x32_bf16 %0, %1, a[" #R0 ":" #R3 "], %0\n\ts_nop 7\n\ts_nop 7" \
      : "+v"(ACC) : "v"(AF))

#define AFENCE asm volatile("" ::: \
  "a0","a1","a2","a3","a4","a5","a6","a7","a8","a9", \
  "a10","a11","a12","a13","a14","a15","a16","a17","a18","a19", \
  "a20","a21","a22","a23","a24","a25","a26","a27","a28","a29", \
  "a30","a31","a32","a33","a34","a35","a36","a37","a38","a39", \
  "a40","a41","a42","a43","a44","a45","a46","a47","a48","a49", \
  "a50","a51","a52","a53","a54","a55","a56","a57","a58","a59", \
  "a60","a61","a62","a63","a64","a65","a66","a67","a68","a69", \
  "a70","a71","a72","a73","a74","a75","a76","a77","a78","a79", \
  "a80","a81","a82","a83","a84","a85","a86","a87","a88","a89", \
  "a90","a91","a92","a93","a94","a95","a96","a97","a98","a99", \
  "a100","a101","a102","a103","a104","a105","a106","a107","a108","a109", \
  "a110","a111","a112","a113","a114","a115","a116","a117","a118","a119", \
  "a120","a121","a122","a123","a124","a125","a126","a127")

// LDS barrier only: LDS writes must be visible (lgkmcnt), global ops need NOT drain
#define LBAR asm volatile("s_waitcnt lgkmcnt(0)\n\ts_barrier" ::: "memory")

// LDS frag slot for (gs,kt), kt=1 absent for gs<2
__device__ __forceinline__ int lfi(int gs, int kt){
  return (gs < 2) ? (gs*2 + (kt ? 1 : 0)) : (4 + (gs-2)*3 + kt);
}

template<int MODE>
__global__ __launch_bounds__(512,2) void gru_scan3(
    const u16* __restrict__ xw,    // [BT,1536] bf16 (= X@K + b0, both dirs)
    const u16* __restrict__ rkT,   // [2][768][256] bf16 transposed recurrent kernels
    const float* __restrict__ bF, const float* __restrict__ bB,  // b[2][768] f32
    u16* __restrict__ h1out,       // MODE 0: [BT,512]
    float* __restrict__ h2out)     // MODE 1: [64,512] final states
{
  int dir = blockIdx.x & 1, bg = blockIdx.x >> 1;
  int b0 = bg*16;
  int tid = threadIdx.x;
  int w = tid>>6, l = tid&63, lc = l&15, quad = l>>4;

  __shared__ u16 rklW[8*16*64*8];  // wave-private B-frags, 16/wave (131,072 B)
  __shared__ u16 hb[2][16][264];   // double-buffered h (16,896 B); tot 147,968 B
  for(int i=tid; i<2*16*264; i+=512) ((u16*)hb)[i] = 0;

  const u16*   rkd  = rkT + (size_t)dir*G3*U_DIM;
  const float* bias = (dir ? bB : bF) + G3;   // row 1 = recurrent bias

  // stage LDS B-frags (16 per wave, lane-contiguous 16B)
  for(int idx=tid; idx<8*16*64; idx+=512){
    int w2 = idx>>10, r = idx&1023, fi = r>>6, lane = r&63;
    int gs, kt;
    if(fi < 4){ gs = fi>>1; kt = (fi&1)*2; }
    else      { int q = fi-4; gs = (q/3)+2; kt = q%3; }
    int n = (gs>>1)*256 + w2*32 + (gs&1)*16 + (lane&15);
    *(s8v*)&rklW[(size_t)idx*8] =
      *(const s8v*)(rkd + (size_t)n*U_DIM + kt*32 + (lane>>4)*8);
  }

  // AGPR frags: kt3..7 -> a0..a119
  INITF(0,0,1,2,3)       INITF(1,4,5,6,7)       INITF(2,8,9,10,11)
  INITF(3,12,13,14,15)   INITF(4,16,17,18,19)   INITF(5,20,21,22,23)
  INITF(6,24,25,26,27)   INITF(7,28,29,30,31)   INITF(8,32,33,34,35)
  INITF(9,36,37,38,39)   INITF(10,40,41,42,43)  INITF(11,44,45,46,47)
  INITF(12,48,49,50,51)  INITF(13,52,53,54,55)  INITF(14,56,57,58,59)
  INITF(15,60,61,62,63)  INITF(16,64,65,66,67)  INITF(17,68,69,70,71)
  INITF(18,72,73,74,75)  INITF(19,76,77,78,79)  INITF(20,80,81,82,83)
  INITF(21,84,85,86,87)  INITF(22,88,89,90,91)  INITF(23,92,93,94,95)
  INITF(24,96,97,98,99)  INITF(25,100,101,102,103) INITF(26,104,105,106,107)
  INITF(27,108,109,110,111) INITF(28,112,113,114,115) INITF(29,116,117,118,119)
  // kt1 for gs0, gs1 -> a120..127
  INITX(w*32 + lc,      1, 120,121,122,123)
  INITX(w*32 + 16 + lc, 1, 124,125,126,127)

  float bgf[3][2];
  #pragma unroll
  for(int g=0;g<3;g++)
    #pragma unroll
    for(int s=0;s<2;s++)
      bgf[g][s] = bias[g*256 + w*32 + s*16 + lc];

  int t0 = dir ? (T_LEN-1) : 0;
  long tstride = dir ? -(long)NTOT      : (long)NTOT;
  long hstride = dir ? -(long)(2*U_DIM) : (long)(2*U_DIM);
  const u16* xwp[4];
  u16* hop[4];
  #pragma unroll
  for(int r=0;r<4;r++){
    int m = quad*4 + r;
    xwp[r] = xw + ((size_t)(b0+m)*T_LEN + t0)*NTOT + dir*G3 + w*32 + lc;
    hop[r] = (MODE==0) ? (h1out + ((size_t)(b0+m)*T_LEN + t0)*(2*U_DIM) + dir*U_DIM + w*32 + lc)
                       : nullptr;
  }

  __syncthreads();

  int cur = 0;
  for(int step=0; step<T_LEN; step++){
    AFENCE;

    // xw preacts (independent of h; consumed late -> latency hidden)
    u16 xu[3][2][4];
    #pragma unroll
    for(int r=0;r<4;r++)
      #pragma unroll
      for(int g=0;g<3;g++)
        #pragma unroll
        for(int s=0;s<2;s++)
          xu[g][s][r] = xwp[r][g*256 + s*16];

    // h(t) reads, first half (kt0..2) + own h_prev
    s8v aA[3];
    #pragma unroll
    for(int kt=0;kt<3;kt++) aA[kt] = *(const s8v*)&hb[cur][lc][kt*32 + quad*8];
    float hp[2][4];
    #pragma unroll
    for(int s=0;s<2;s++)
      #pragma unroll
      for(int r=0;r<4;r++)
        hp[s][r] = bf2f(hb[cur][quad*4+r][w*32 + s*16 + lc]);

    f4v acc[3][2];
    s8v bl[6];
    // kt0: all 6 from LDS (inline C=0 -> no VALU-init hazard)
    #pragma unroll
    for(int g=0;g<3;g++)
      #pragma unroll
      for(int s=0;s<2;s++)
        bl[g*2+s] = *(const s8v*)&rklW[(size_t)((w*16 + lfi(g*2+s,0))*64 + l)*8];
    MFZ(acc[0][0],aA[0],bl[0]);  MFZ(acc[0][1],aA[0],bl[1]);
    MFZ(acc[1][0],aA[0],bl[2]);  MFZ(acc[1][1],aA[0],bl[3]);
    MFZ(acc[2][0],aA[0],bl[4]);  MFZ(acc[2][1],aA[0],bl[5]);
    // kt1: gs0/gs1 from AGPR, gs2..5 from LDS
    #pragma unroll
    for(int g=1;g<3;g++)
      #pragma unroll
      for(int s=0;s<2;s++)
        bl[g*2+s] = *(const s8v*)&rklW[(size_t)((w*16 + lfi(g*2+s,1))*64 + l)*8];
    MFA(acc[0][0],aA[1],120,123);  MFA(acc[0][1],aA[1],124,127);
    MFV(acc[1][0],aA[1],bl[2]);    MFV(acc[1][1],aA[1],bl[3]);
    MFV(acc[2][0],aA[1],bl[4]);    MFV(acc[2][1],aA[1],bl[5]);
    // kt2: all 6 from LDS
    #pragma unroll
    for(int g=0;g<3;g++)
      #pragma unroll
      for(int s=0;s<2;s++)
        bl[g*2+s] = *(const s8v*)&rklW[(size_t)((w*16 + lfi(g*2+s,2))*64 + l)*8];
    MFV(acc[0][0],aA[2],bl[0]);  MFV(acc[0][1],aA[2],bl[1]);
    MFV(acc[1][0],aA[2],bl[2]);  MFV(acc[1][1],aA[2],bl[3]);
    MFV(acc[2][0],aA[2],bl[4]);  MFV(acc[2][1],aA[2],bl[5]);

    // h(t) reads, second half (kt3..7) — areg reg reuse keeps pressure low
    s8v aB[5];
    #pragma unroll
    for(int kt=0;kt<5;kt++) aB[kt] = *(const s8v*)&hb[cur][lc][(kt+3)*32 + quad*8];
    // kt3..6 (AGPR B)
    MFA(acc[0][0],aB[0],0,3);    MFA(acc[0][1],aB[0],20,23);
    MFA(acc[1][0],aB[0],40,43);  MFA(acc[1][1],aB[0],60,63);
    MFA(acc[2][0],aB[0],80,83);  MFA(acc[2][1],aB[0],100,103);
    MFA(acc[0][0],aB[1],4,7);    MFA(acc[0][1],aB[1],24,27);
    MFA(acc[1][0],aB[1],44,47);  MFA(acc[1][1],aB[1],64,67);
    MFA(acc[2][0],aB[1],84,87);  MFA(acc[2][1],aB[1],104,107);
    MFA(acc[0][0],aB[2],8,11);   MFA(acc[0][1],aB[2],28,31);
    MFA(acc[1][0],aB[2],48,51);  MFA(acc[1][1],aB[2],68,71);
    MFA(acc[2][0],aB[2],88,91);  MFA(acc[2][1],aB[2],108,111);
    MFA(acc[0][0],aB[3],12,15);  MFA(acc[0][1],aB[3],32,35);
    MFA(acc[1][0],aB[3],52,55);  MFA(acc[1][1],aB[3],72,75);
    MFA(acc[2][0],aB[3],92,95);  MFA(acc[2][1],aB[3],112,115);
    // kt7 last in each chain: trailing drain nops
    MFAE(acc[0][0],aB[4],16,19);  MFAE(acc[0][1],aB[4],36,39);
    MFAE(acc[1][0],aB[4],56,59);  MFAE(acc[1][1],aB[4],76,79);
    MFAE(acc[2][0],aB[4],96,99);  MFAE(acc[2][1],aB[4],116,119);

    AFENCE;

    // gates + state update (cheap forms; no clamp — rcp laundering is NaN-safe)
    #pragma unroll
    for(int s=0;s<2;s++){
      int u = w*32 + s*16 + lc;
      #pragma unroll
      for(int r=0;r<4;r++){
        int m = quad*4 + r;
        float zf = acc[0][s][r] + bgf[0][s] + bf2f(xu[0][s][r]);
        float rf = acc[1][s][r] + bgf[1][s] + bf2f(xu[1][s][r]);
        float rh = acc[2][s][r] + bgf[2][s];
        float xh = bf2f(xu[2][s][r]);
        zf = __builtin_amdgcn_rcpf(1.f + __expf(-zf));
        rf = __builtin_amdgcn_rcpf(1.f + __expf(-rf));
        float hc = xh + rf*rh;
        float e2 = __expf(2.f*hc);
        float th = 1.f - 2.f*__builtin_amdgcn_rcpf(e2 + 1.f);
        float hn = th + zf*(hp[s][r] - th);
        u16 hbf = f2bf(hn);
        hb[cur^1][m][u] = hbf;
        if(MODE == 0)
          hop[r][s*16] = hbf;
        else if(step == T_LEN-1)
          h2out[(size_t)(b0+m)*(2*U_DIM) + dir*U_DIM + u] = hn;
      }
    }

    #pragma unroll
    for(int r=0;r<4;r++){
      xwp[r] += tstride;
      if(MODE==0) hop[r] += hstride;
    }
    LBAR;          // lgkmcnt-only barrier: no vmcnt drain of xu loads / h1 stores
    cur ^= 1;
  }
}

// ---------------- final projection + softmax (f32 output) ---------------------
__global__ void out_softmax(const float* __restrict__ h2, const float* __restrict__ wout,
                            const float* __restrict__ bout, float* __restrict__ out)
{
  __shared__ float lg[C_DIM];
  int b = blockIdx.x, l = threadIdx.x;   // 64 threads = 1 wave
  float acc[C_DIM];
  #pragma unroll
  for(int c=0;c<C_DIM;c++) acc[c] = 0.f;
  for(int k=l; k<2*U_DIM; k+=64){
    float hv = h2[b*2*U_DIM + k];
    #pragma unroll
    for(int c=0;c<C_DIM;c++) acc[c] += hv * wout[k*C_DIM + c];
  }
  #pragma unroll
  for(int c=0;c<C_DIM;c++){
    float v = acc[c];
    for(int off=32; off; off>>=1) v += __shfl_down(v, off);
    if(l==0) lg[c] = v + bout[c];
  }
  __syncthreads();
  if(l==0){
    float mx = lg[0];
    for(int c=1;c<C_DIM;c++) mx = fmaxf(mx, lg[c]);
    float sum = 0.f, ex[C_DIM];
    for(int c=0;c<C_DIM;c++){ ex[c] = __expf(lg[c]-mx); sum += ex[c]; }
    for(int c=0;c<C_DIM;c++) out[b*C_DIM + c] = ex[c]/sum;
  }
}

extern "C" void kernel_launch(void* const* d_in, const int* in_sizes, int n_in,
                              void* d_out, int out_size, void* d_ws, size_t ws_size,
                              hipStream_t stream)
{
  const int*   x    = (const int*)d_in[0];
  const float* emb  = (const float*)d_in[1];
  const float* k1f  = (const float*)d_in[2];
  const float* rk1f = (const float*)d_in[3];
  const float* b1f  = (const float*)d_in[4];
  const float* k1b  = (const float*)d_in[5];
  const float* rk1b = (const float*)d_in[6];
  const float* b1b  = (const float*)d_in[7];
  const float* k2f  = (const float*)d_in[8];
  const float* rk2f = (const float*)d_in[9];
  const float* b2f  = (const float*)d_in[10];
  const float* k2b  = (const float*)d_in[11];
  const float* rk2b = (const float*)d_in[12];
  const float* b2b  = (const float*)d_in[13];
  const float* wout = (const float*)d_in[14];
  const float* bout = (const float*)d_in[15];

  char* ws = (char*)d_ws;
  u16*  k1t   = (u16*)(ws);                       // 983,040 B     [1536,320]
  u16*  k2t   = (u16*)(ws + 983040);              // 1,572,864 B   [1536,512]
  u16*  rkt   = (u16*)(ws + 2555904);             // 1,572,864 B   4x[768,256]
  float* h2   = (float*)(ws + 4128768);           // 131,072 B     [64,512]
  u16*  h1    = (u16*)(ws + 4259840);             // 33,554,432 B  [BT,512]
  u16*  e_pad = (u16*)(ws + 4259840);             // (alias h1)
  u16*  xwb   = (u16*)(ws + 37814272);            // 100,663,296 B [BT,1536]

  transpose_cc<<<(NTOT*EP +255)/256,256,0,stream>>>(k1f, k1b, k1t, E_DIM, EP, NTOT);
  transpose_cc<<<(NTOT*512+255)/256,256,0,stream>>>(k2f, k2b, k2t, 512, 512, NTOT);
  transpose_cc<<<(G3*U_DIM+255)/256,256,0,stream>>>(rk1f, rk1f, rkt,                U_DIM, U_DIM, G3);
  transpose_cc<<<(G3*U_DIM+255)/256,256,0,stream>>>(rk1b, rk1b, rkt + 1*G3*U_DIM,   U_DIM, U_DIM, G3);
  transpose_cc<<<(G3*U_DIM+255)/256,256,0,stream>>>(rk2f, rk2f, rkt + 2*G3*U_DIM,   U_DIM, U_DIM, G3);
  transpose_cc<<<(G3*U_DIM+255)/256,256,0,stream>>>(rk2b, rk2b, rkt + 3*G3*U_DIM,   U_DIM, U_DIM, G3);

  embed_pad<<<(BT*EP)/256,256,0,stream>>>(x, emb, e_pad);

  // layer 1: xw = e @ K1 + b0 ; scan -> h1
  gemm_bt<<<dim3(12,256),256,0,stream>>>(e_pad, k1t, xwb, EP, b1f, b1b);
  gru_scan3<0><<<8,512,0,stream>>>(xwb, rkt, b1f, b1b, h1, nullptr);

  // layer 2: xw = h1 @ K2 + b0 ; scan -> h2 (final states only)
  gemm_bt<<<dim3(12,256),256,0,stream>>>(h1, k2t, xwb, 512, b2f, b2b);
  gru_scan3<1><<<8,512,0,stream>>>(xwb, rkt + 2*G3*U_DIM, b2f, b2b, nullptr, h2);

  out_softmax<<<64,64,0,stream>>>(h2, wout, bout, (float*)d_out);
}

// Round 13
// 2183.808 us; speedup vs baseline: 1.8253x; 1.3094x over previous
//
#include <hip/hip_runtime.h>

typedef unsigned short u16;
typedef unsigned int   u32;
typedef __attribute__((ext_vector_type(8))) short s8v;   // 8 x bf16 bits (4 VGPRs)
typedef __attribute__((ext_vector_type(4))) float f4v;   // MFMA accumulator
typedef __attribute__((ext_vector_type(4))) int   i4v;   // 4 VGPRs (generic 16B)

#define B_SZ  64
#define T_LEN 512
#define U_DIM 256
#define E_DIM 300
#define EP    320          // E padded to multiple of 32
#define G3    768          // 3*U
#define NTOT  1536         // both directions concatenated
#define C_DIM 20
#define BT    (B_SZ*T_LEN)

__device__ __forceinline__ float bf2f(u16 h){ return __uint_as_float(((u32)h)<<16); }
__device__ __forceinline__ u16 f2bf(float f){
  u32 u = __float_as_uint(f);
  u32 r = (u + 0x7FFFu + ((u>>16)&1u)) >> 16;   // RNE
  return (u16)r;
}

// ------------- embedding gather f32 -> bf16, K-pad (300 -> 320, zeros) --------
__global__ void embed_pad(const int* __restrict__ x, const float* __restrict__ emb,
                          u16* __restrict__ e){
  int idx = blockIdx.x*256 + threadIdx.x;
  if(idx >= BT*EP) return;
  int row = idx / EP, col = idx - row*EP;
  u16 v = 0;
  if(col < E_DIM) v = f2bf(emb[(size_t)x[row]*E_DIM + col]);
  e[idx] = v;
}

// ------ transpose + concat two f32 [K,768] sources -> bf16 dst[N][Kp] ---------
__global__ void transpose_cc(const float* __restrict__ A, const float* __restrict__ Bm,
                             u16* __restrict__ dst, int K, int Kp, int N){
  int idx = blockIdx.x*256 + threadIdx.x;
  if(idx >= N*Kp) return;
  int n = idx / Kp, k = idx - n*Kp;
  u16 v = 0;
  if(k < K){
    const float* s = (n < G3) ? A : Bm;
    int nn = (n < G3) ? n : n - G3;
    v = f2bf(s[(size_t)k*G3 + nn]);
  }
  dst[idx] = v;
}

// ------- GEMM: xq[dir][bg][t][g][tid][8] = A[M,Kp] @ BT^T + bias (bf16) -------
// Writes the scan-native packed layout directly: cell (s,r) of gate g for scan
// thread tid at time t lives at (((dir*4+bg)*512+t)*3+g)*4096 + tid*8 + s*4+r.
__global__ __launch_bounds__(256) void gemm_bt(
    const u16* __restrict__ A, const u16* __restrict__ BT_, u16* __restrict__ Cq,
    int Kp, const float* __restrict__ biasA, const float* __restrict__ biasB)
{
  __shared__ u16 Al[128][40];   // +8 pad breaks bank collisions
  __shared__ u16 Bl[128][40];
  int tid = threadIdx.x;
  int w = tid>>6, l = tid&63, lc = l&15, quad = l>>4;
  int wm = w>>1, wn = w&1;
  int mb = blockIdx.y*128, nb = blockIdx.x*128;

  f4v acc[4][4];
  #pragma unroll
  for(int i=0;i<4;i++)
    #pragma unroll
    for(int j=0;j<4;j++) acc[i][j] = (f4v){0.f,0.f,0.f,0.f};

  int nk = Kp >> 5;
  for(int kt=0; kt<nk; kt++){
    __syncthreads();
    {
      int c0 = tid, c1 = tid + 256;
      int r0 = c0>>2, k80 = c0&3;
      int r1 = c1>>2, k81 = c1&3;
      *(s8v*)&Al[r0][k80*8] = *(const s8v*)(A   + (size_t)(mb+r0)*Kp + kt*32 + k80*8);
      *(s8v*)&Al[r1][k81*8] = *(const s8v*)(A   + (size_t)(mb+r1)*Kp + kt*32 + k81*8);
      *(s8v*)&Bl[r0][k80*8] = *(const s8v*)(BT_ + (size_t)(nb+r0)*Kp + kt*32 + k80*8);
      *(s8v*)&Bl[r1][k81*8] = *(const s8v*)(BT_ + (size_t)(nb+r1)*Kp + kt*32 + k81*8);
    }
    __syncthreads();
    s8v af[4], bf[4];
    #pragma unroll
    for(int i=0;i<4;i++) af[i] = *(const s8v*)&Al[wm*64 + i*16 + lc][quad*8];
    #pragma unroll
    for(int j=0;j<4;j++) bf[j] = *(const s8v*)&Bl[wn*64 + j*16 + lc][quad*8];
    #pragma unroll
    for(int i=0;i<4;i++)
      #pragma unroll
      for(int j=0;j<4;j++)
        acc[i][j] = __builtin_amdgcn_mfma_f32_16x16x32_bf16(af[i], bf[j], acc[i][j],0,0,0);
  }

  // permuted epilogue: row = b*512 + t (tile spans one b); col -> (dir,g,u)
  int b  = mb >> 9;
  int bg = b >> 4, m = b & 15, quad_s = m >> 2, r_s = m & 3;
  int tb = (mb & 511) + wm*64;
  #pragma unroll
  for(int j=0;j<4;j++){
    int col = nb + wn*64 + j*16 + lc;
    float bias = (col < G3) ? biasA[col] : biasB[col - G3];
    int dir = (col >= G3) ? 1 : 0;
    int c7  = col - dir*G3;
    int g   = c7 >> 8, u = c7 & 255;
    int w_s = u>>5, rem = u&31, s = rem>>4, lc_s = rem&15;
    size_t cb = ((size_t)(dir*4+bg)*512*3 + g)*4096
              + (size_t)((w_s*64 + quad_s*16 + lc_s)*8 + s*4 + r_s);
    #pragma unroll
    for(int i=0;i<4;i++){
      #pragma unroll
      for(int r=0;r<4;r++){
        int t = tb + i*16 + quad*4 + r;
        Cq[cb + (size_t)t*12288] = f2bf(acc[i][j][r] + bias);
      }
    }
  }
}

// ---------------- GRU scan: hard-coded AGPR + LDS residency (v4) --------------
// 8 blocks (dir = blk&1, bg = blk>>1, M=16). 512 threads = 8 waves; wave w owns
// u in [32w,32w+32) -> 96 gate-cols.
//   AGPR (128/128): kt3..7 all gs -> a0..a119; kt1 gs0/gs1 -> a120..127.
//   LDS: remaining 16 frags/wave, wave-private lane-contiguous 16B.
// v4 vs R12: xw preacts via 3x dwordx4 from packed xq (-21 VMEM/thread/step),
// h_prev carried in f32 registers (-8 LDS reads/wave/step).

#define INITF(F,A0,A1,A2,A3) { \
  i4v t = *(const i4v*)(rkd + (size_t)((F/10)*256 + w*32 + ((F/5)&1)*16 + lc)*U_DIM \
                            + ((F%5)+3)*32 + quad*8); \
  asm volatile("v_accvgpr_write_b32 a" #A0 ", %0\n\t" \
               "v_accvgpr_write_b32 a" #A1 ", %1\n\t" \
               "v_accvgpr_write_b32 a" #A2 ", %2\n\t" \
               "v_accvgpr_write_b32 a" #A3 ", %3" \
               :: "v"(t[0]), "v"(t[1]), "v"(t[2]), "v"(t[3]) \
               : "a" #A0, "a" #A1, "a" #A2, "a" #A3); }

#define INITX(NOFF,KT,A0,A1,A2,A3) { \
  i4v t = *(const i4v*)(rkd + (size_t)(NOFF)*U_DIM + (KT)*32 + quad*8); \
  asm volatile("v_accvgpr_write_b32 a" #A0 ", %0\n\t" \
               "v_accvgpr_write_b32 a" #A1 ", %1\n\t" \
               "v_accvgpr_write_b32 a" #A2 ", %2\n\t" \
               "v_accvgpr_write_b32 a" #A3 ", %3" \
               :: "v"(t[0]), "v"(t[1]), "v"(t[2]), "v"(t[3]) \
               : "a" #A0, "a" #A1, "a" #A2, "a" #A3); }

#define MFZ(ACC,AF,BF) \
  asm("v_mfma_f32_16x16x32_bf16 %0, %1, %2, 0" : "=&v"(ACC) : "v"(AF), "v"(BF))
#define MFA(ACC,AF,R0,R3) \
  asm("v_mfma_f32_16x16x32_bf16 %0, %1, a[" #R0 ":" #R3 "], %0" \
      : "+v"(ACC) : "v"(AF))
#define MFV(ACC,AF,BF) \
  asm("v_mfma_f32_16x16x32_bf16 %0, %1, %2, %0" : "+v"(ACC) : "v"(AF), "v"(BF))
#define MFAE(ACC,AF,R0,R3) \
  asm("v_mfma_f32_16x16x32_bf16 %0, %1, a[" #R0 ":" #R3 "], %0\n\ts_nop 7\n\ts_nop 7" \
      : "+v"(ACC) : "v"(AF))

#define AFENCE asm volatile("" ::: \
  "a0","a1","a2","a3","a4","a5","a6","a7","a8","a9", \
  "a10","a11","a12","a13","a14","a15","a16","a17","a18","a19", \
  "a20","a21","a22","a23","a24","a25","a26","a27","a28","a29", \
  "a30","a31","a32","a33","a34","a35","a36","a37","a38","a39", \
  "a40","a41","a42","a43","a44","a45","a46","a47","a48","a49", \
  "a50","a51","a52","a53","a54","a55","a56","a57","a58","a59", \
  "a60","a61","a62","a63","a64","a65","a66","a67","a68","a69", \
  "a70","a71","a72","a73","a74","a75","a76","a77","a78","a79", \
  "a80","a81","a82","a83","a84","a85","a86","a87","a88","a89", \
  "a90","a91","a92","a93","a94","a95","a96","a97","a98","a99", \
  "a100","a101","a102","a103","a104","a105","a106","a107","a108","a109", \
  "a110","a111","a112","a113","a114","a115","a116","a117","a118","a119", \
  "a120","a121","a122","a123","a124","a125","a126","a127")

#define LBAR asm volatile("s_waitcnt lgkmcnt(0)\n\ts_barrier" ::: "memory")

__device__ __forceinline__ int lfi(int gs, int kt){
  return (gs < 2) ? (gs*2 + (kt ? 1 : 0)) : (4 + (gs-2)*3 + kt);
}

template<int MODE>
__global__ __launch_bounds__(512,2) void gru_scan3(
    const u16* __restrict__ xq,    // packed preacts (see gemm_bt)
    const u16* __restrict__ rkT,   // [2][768][256] bf16 transposed recurrent kernels
    const float* __restrict__ bF, const float* __restrict__ bB,  // b[2][768] f32
    u16* __restrict__ h1out,       // MODE 0: [BT,512]
    float* __restrict__ h2out)     // MODE 1: [64,512] final states
{
  int dir = blockIdx.x & 1, bg = blockIdx.x >> 1;
  int b0 = bg*16;
  int tid = threadIdx.x;
  int w = tid>>6, l = tid&63, lc = l&15, quad = l>>4;

  __shared__ u16 rklW[8*16*64*8];  // wave-private B-frags, 16/wave (131,072 B)
  __shared__ u16 hb[2][16][264];   // double-buffered h (16,896 B)
  for(int i=tid; i<2*16*264; i+=512) ((u16*)hb)[i] = 0;

  const u16*   rkd  = rkT + (size_t)dir*G3*U_DIM;
  const float* bias = (dir ? bB : bF) + G3;   // row 1 = recurrent bias

  // stage LDS B-frags (16 per wave, lane-contiguous 16B)
  for(int idx=tid; idx<8*16*64; idx+=512){
    int w2 = idx>>10, r = idx&1023, fi = r>>6, lane = r&63;
    int gs, kt;
    if(fi < 4){ gs = fi>>1; kt = (fi&1)*2; }
    else      { int q = fi-4; gs = (q/3)+2; kt = q%3; }
    int n = (gs>>1)*256 + w2*32 + (gs&1)*16 + (lane&15);
    *(s8v*)&rklW[(size_t)idx*8] =
      *(const s8v*)(rkd + (size_t)n*U_DIM + kt*32 + (lane>>4)*8);
  }

  // AGPR frags: kt3..7 -> a0..a119
  INITF(0,0,1,2,3)       INITF(1,4,5,6,7)       INITF(2,8,9,10,11)
  INITF(3,12,13,14,15)   INITF(4,16,17,18,19)   INITF(5,20,21,22,23)
  INITF(6,24,25,26,27)   INITF(7,28,29,30,31)   INITF(8,32,33,34,35)
  INITF(9,36,37,38,39)   INITF(10,40,41,42,43)  INITF(11,44,45,46,47)
  INITF(12,48,49,50,51)  INITF(13,52,53,54,55)  INITF(14,56,57,58,59)
  INITF(15,60,61,62,63)  INITF(16,64,65,66,67)  INITF(17,68,69,70,71)
  INITF(18,72,73,74,75)  INITF(19,76,77,78,79)  INITF(20,80,81,82,83)
  INITF(21,84,85,86,87)  INITF(22,88,89,90,91)  INITF(23,92,93,94,95)
  INITF(24,96,97,98,99)  INITF(25,100,101,102,103) INITF(26,104,105,106,107)
  INITF(27,108,109,110,111) INITF(28,112,113,114,115) INITF(29,116,117,118,119)
  INITX(w*32 + lc,      1, 120,121,122,123)
  INITX(w*32 + 16 + lc, 1, 124,125,126,127)

  float bgf[3][2];
  #pragma unroll
  for(int g=0;g<3;g++)
    #pragma unroll
    for(int s=0;s<2;s++)
      bgf[g][s] = bias[g*256 + w*32 + s*16 + lc];

  int t0 = dir ? (T_LEN-1) : 0;
  long qstride = dir ? -12288L : 12288L;             // xq u16-elems per step
  long hstride = dir ? -(long)(2*U_DIM) : (long)(2*U_DIM);
  const u16* xqp = xq + ((size_t)(dir*4+bg)*512 + t0)*12288 + (size_t)tid*8;
  u16* hop[4];
  #pragma unroll
  for(int r=0;r<4;r++){
    int m = quad*4 + r;
    hop[r] = (MODE==0) ? (h1out + ((size_t)(b0+m)*T_LEN + t0)*(2*U_DIM) + dir*U_DIM + w*32 + lc)
                       : nullptr;
  }

  float hpc[2][4];   // carried h_prev (own cells), f32
  #pragma unroll
  for(int s=0;s<2;s++)
    #pragma unroll
    for(int r=0;r<4;r++) hpc[s][r] = 0.f;

  __syncthreads();

  int cur = 0;
  for(int step=0; step<T_LEN; step++){
    AFENCE;

    // packed xw preacts: 3 x dwordx4 (gate g at +g*4096 u16)
    i4v c0 = *(const i4v*)(xqp);
    i4v c1 = *(const i4v*)(xqp + 4096);
    i4v c2 = *(const i4v*)(xqp + 8192);

    // h(t) reads, first half (kt0..2)
    s8v aA[3];
    #pragma unroll
    for(int kt=0;kt<3;kt++) aA[kt] = *(const s8v*)&hb[cur][lc][kt*32 + quad*8];

    f4v acc[3][2];
    s8v bl[6];
    // kt0: all 6 from LDS (inline C=0)
    #pragma unroll
    for(int g=0;g<3;g++)
      #pragma unroll
      for(int s=0;s<2;s++)
        bl[g*2+s] = *(const s8v*)&rklW[(size_t)((w*16 + lfi(g*2+s,0))*64 + l)*8];
    MFZ(acc[0][0],aA[0],bl[0]);  MFZ(acc[0][1],aA[0],bl[1]);
    MFZ(acc[1][0],aA[0],bl[2]);  MFZ(acc[1][1],aA[0],bl[3]);
    MFZ(acc[2][0],aA[0],bl[4]);  MFZ(acc[2][1],aA[0],bl[5]);
    // kt1: gs0/gs1 from AGPR, gs2..5 from LDS
    #pragma unroll
    for(int g=1;g<3;g++)
      #pragma unroll
      for(int s=0;s<2;s++)
        bl[g*2+s] = *(const s8v*)&rklW[(size_t)((w*16 + lfi(g*2+s,1))*64 + l)*8];
    MFA(acc[0][0],aA[1],120,123);  MFA(acc[0][1],aA[1],124,127);
    MFV(acc[1][0],aA[1],bl[2]);    MFV(acc[1][1],aA[1],bl[3]);
    MFV(acc[2][0],aA[1],bl[4]);    MFV(acc[2][1],aA[1],bl[5]);
    // kt2: all 6 from LDS
    #pragma unroll
    for(int g=0;g<3;g++)
      #pragma unroll
      for(int s=0;s<2;s++)
        bl[g*2+s] = *(const s8v*)&rklW[(size_t)((w*16 + lfi(g*2+s,2))*64 + l)*8];
    MFV(acc[0][0],aA[2],bl[0]);  MFV(acc[0][1],aA[2],bl[1]);
    MFV(acc[1][0],aA[2],bl[2]);  MFV(acc[1][1],aA[2],bl[3]);
    MFV(acc[2][0],aA[2],bl[4]);  MFV(acc[2][1],aA[2],bl[5]);

    // h(t) reads, second half (kt3..7)
    s8v aB[5];
    #pragma unroll
    for(int kt=0;kt<5;kt++) aB[kt] = *(const s8v*)&hb[cur][lc][(kt+3)*32 + quad*8];
    MFA(acc[0][0],aB[0],0,3);    MFA(acc[0][1],aB[0],20,23);
    MFA(acc[1][0],aB[0],40,43);  MFA(acc[1][1],aB[0],60,63);
    MFA(acc[2][0],aB[0],80,83);  MFA(acc[2][1],aB[0],100,103);
    MFA(acc[0][0],aB[1],4,7);    MFA(acc[0][1],aB[1],24,27);
    MFA(acc[1][0],aB[1],44,47);  MFA(acc[1][1],aB[1],64,67);
    MFA(acc[2][0],aB[1],84,87);  MFA(acc[2][1],aB[1],104,107);
    MFA(acc[0][0],aB[2],8,11);   MFA(acc[0][1],aB[2],28,31);
    MFA(acc[1][0],aB[2],48,51);  MFA(acc[1][1],aB[2],68,71);
    MFA(acc[2][0],aB[2],88,91);  MFA(acc[2][1],aB[2],108,111);
    MFA(acc[0][0],aB[3],12,15);  MFA(acc[0][1],aB[3],32,35);
    MFA(acc[1][0],aB[3],52,55);  MFA(acc[1][1],aB[3],72,75);
    MFA(acc[2][0],aB[3],92,95);  MFA(acc[2][1],aB[3],112,115);
    MFAE(acc[0][0],aB[4],16,19);  MFAE(acc[0][1],aB[4],36,39);
    MFAE(acc[1][0],aB[4],56,59);  MFAE(acc[1][1],aB[4],76,79);
    MFAE(acc[2][0],aB[4],96,99);  MFAE(acc[2][1],aB[4],116,119);

    AFENCE;

    // gates + state update; xw inputs unpacked from c0/c1/c2
    #pragma unroll
    for(int s=0;s<2;s++){
      int u = w*32 + s*16 + lc;
      #pragma unroll
      for(int r=0;r<4;r++){
        int m = quad*4 + r;
        int k = s*4 + r, ki = k>>1;
        float xz, xr, xh;
        if(k & 1){
          xz = __uint_as_float(((u32)c0[ki]) & 0xffff0000u);
          xr = __uint_as_float(((u32)c1[ki]) & 0xffff0000u);
          xh = __uint_as_float(((u32)c2[ki]) & 0xffff0000u);
        } else {
          xz = __uint_as_float(((u32)c0[ki]) << 16);
          xr = __uint_as_float(((u32)c1[ki]) << 16);
          xh = __uint_as_float(((u32)c2[ki]) << 16);
        }
        float zf = acc[0][s][r] + bgf[0][s] + xz;
        float rf = acc[1][s][r] + bgf[1][s] + xr;
        float rh = acc[2][s][r] + bgf[2][s];
        zf = __builtin_amdgcn_rcpf(1.f + __expf(-zf));
        rf = __builtin_amdgcn_rcpf(1.f + __expf(-rf));
        float hc = xh + rf*rh;
        float e2 = __expf(2.f*hc);
        float th = 1.f - 2.f*__builtin_amdgcn_rcpf(e2 + 1.f);
        float hn = th + zf*(hpc[s][r] - th);
        hpc[s][r] = hn;
        u16 hbf = f2bf(hn);
        hb[cur^1][m][u] = hbf;
        if(MODE == 0)
          hop[r][s*16] = hbf;
        else if(step == T_LEN-1)
          h2out[(size_t)(b0+m)*(2*U_DIM) + dir*U_DIM + u] = hn;
      }
    }

    xqp += qstride;
    if(MODE==0){
      #pragma unroll
      for(int r=0;r<4;r++) hop[r] += hstride;
    }
    LBAR;
    cur ^= 1;
  }
}

// ---------------- final projection + softmax (f32 output) ---------------------
__global__ void out_softmax(const float* __restrict__ h2, const float* __restrict__ wout,
                            const float* __restrict__ bout, float* __restrict__ out)
{
  __shared__ float lg[C_DIM];
  int b = blockIdx.x, l = threadIdx.x;   // 64 threads = 1 wave
  float acc[C_DIM];
  #pragma unroll
  for(int c=0;c<C_DIM;c++) acc[c] = 0.f;
  for(int k=l; k<2*U_DIM; k+=64){
    float hv = h2[b*2*U_DIM + k];
    #pragma unroll
    for(int c=0;c<C_DIM;c++) acc[c] += hv * wout[k*C_DIM + c];
  }
  #pragma unroll
  for(int c=0;c<C_DIM;c++){
    float v = acc[c];
    for(int off=32; off; off>>=1) v += __shfl_down(v, off);
    if(l==0) lg[c] = v + bout[c];
  }
  __syncthreads();
  if(l==0){
    float mx = lg[0];
    for(int c=1;c<C_DIM;c++) mx = fmaxf(mx, lg[c]);
    float sum = 0.f, ex[C_DIM];
    for(int c=0;c<C_DIM;c++){ ex[c] = __expf(lg[c]-mx); sum += ex[c]; }
    for(int c=0;c<C_DIM;c++) out[b*C_DIM + c] = ex[c]/sum;
  }
}

extern "C" void kernel_launch(void* const* d_in, const int* in_sizes, int n_in,
                              void* d_out, int out_size, void* d_ws, size_t ws_size,
                              hipStream_t stream)
{
  const int*   x    = (const int*)d_in[0];
  const float* emb  = (const float*)d_in[1];
  const float* k1f  = (const float*)d_in[2];
  const float* rk1f = (const float*)d_in[3];
  const float* b1f  = (const float*)d_in[4];
  const float* k1b  = (const float*)d_in[5];
  const float* rk1b = (const float*)d_in[6];
  const float* b1b  = (const float*)d_in[7];
  const float* k2f  = (const float*)d_in[8];
  const float* rk2f = (const float*)d_in[9];
  const float* b2f  = (const float*)d_in[10];
  const float* k2b  = (const float*)d_in[11];
  const float* rk2b = (const float*)d_in[12];
  const float* b2b  = (const float*)d_in[13];
  const float* wout = (const float*)d_in[14];
  const float* bout = (const float*)d_in[15];

  char* ws = (char*)d_ws;
  u16*  k1t   = (u16*)(ws);                       // 983,040 B     [1536,320]
  u16*  k2t   = (u16*)(ws + 983040);              // 1,572,864 B   [1536,512]
  u16*  rkt   = (u16*)(ws + 2555904);             // 1,572,864 B   4x[768,256]
  float* h2   = (float*)(ws + 4128768);           // 131,072 B     [64,512]
  u16*  h1    = (u16*)(ws + 4259840);             // 33,554,432 B  [BT,512]
  u16*  e_pad = (u16*)(ws + 4259840);             // (alias h1)
  u16*  xq    = (u16*)(ws + 37814272);            // 100,663,296 B packed preacts

  transpose_cc<<<(NTOT*EP +255)/256,256,0,stream>>>(k1f, k1b, k1t, E_DIM, EP, NTOT);
  transpose_cc<<<(NTOT*512+255)/256,256,0,stream>>>(k2f, k2b, k2t, 512, 512, NTOT);
  transpose_cc<<<(G3*U_DIM+255)/256,256,0,stream>>>(rk1f, rk1f, rkt,                U_DIM, U_DIM, G3);
  transpose_cc<<<(G3*U_DIM+255)/256,256,0,stream>>>(rk1b, rk1b, rkt + 1*G3*U_DIM,   U_DIM, U_DIM, G3);
  transpose_cc<<<(G3*U_DIM+255)/256,256,0,stream>>>(rk2f, rk2f, rkt + 2*G3*U_DIM,   U_DIM, U_DIM, G3);
  transpose_cc<<<(G3*U_DIM+255)/256,256,0,stream>>>(rk2b, rk2b, rkt + 3*G3*U_DIM,   U_DIM, U_DIM, G3);

  embed_pad<<<(BT*EP)/256,256,0,stream>>>(x, emb, e_pad);

  // layer 1: xq = pack(e @ K1 + b0) ; scan -> h1
  gemm_bt<<<dim3(12,256),256,0,stream>>>(e_pad, k1t, xq, EP, b1f, b1b);
  gru_scan3<0><<<8,512,0,stream>>>(xq, rkt, b1f, b1b, h1, nullptr);

  // layer 2: xq = pack(h1 @ K2 + b0) ; scan -> h2 (final states only)
  gemm_bt<<<dim3(12,256),256,0,stream>>>(h1, k2t, xq, 512, b2f, b2b);
  gru_scan3<1><<<8,512,0,stream>>>(xq, rkt + 2*G3*U_DIM, b2f, b2b, nullptr, h2);

  out_softmax<<<64,64,0,stream>>>(h2, wout, bout, (float*)d_out);
}